// Round 9
// baseline (2339.076 us; speedup 1.0000x reference)
//
#include <hip/hip_runtime.h>
#include <cstdint>
#include <cstddef>

#define NB 8
#define NPT 8192
#define NS 1024
#define NK 32
static constexpr int N = NB * NS * NK;  // 262144 grouped points

typedef float v2f __attribute__((ext_vector_type(2)));
typedef unsigned long long u64;

// ---------------- DPP helpers ----------------
// wave64 sum-reduce; valid result in lane 63 only.
__device__ __forceinline__ float wave_sum63(float v) {
  v += __int_as_float(__builtin_amdgcn_update_dpp(0, __float_as_int(v), 0x111, 0xf, 0xf, true));
  v += __int_as_float(__builtin_amdgcn_update_dpp(0, __float_as_int(v), 0x112, 0xf, 0xf, true));
  v += __int_as_float(__builtin_amdgcn_update_dpp(0, __float_as_int(v), 0x114, 0xf, 0xf, true));
  v += __int_as_float(__builtin_amdgcn_update_dpp(0, __float_as_int(v), 0x118, 0xf, 0xf, true));
  v += __int_as_float(__builtin_amdgcn_update_dpp(0, __float_as_int(v), 0x142, 0xa, 0xf, true));
  v += __int_as_float(__builtin_amdgcn_update_dpp(0, __float_as_int(v), 0x143, 0xc, 0xf, true));
  return v;
}

// ---------------- FPS: packed-u64 DPP argmax, coords fetched from LDS ----------------
#define FPS_DPP_STEP_PK(ctrl, rmask)                                                      \
  {                                                                                       \
    unsigned lo = (unsigned)pk, hi = (unsigned)(pk >> 32);                                \
    unsigned slo = __builtin_amdgcn_update_dpp(lo, lo, ctrl, rmask, 0xf, false);          \
    unsigned shi = __builtin_amdgcn_update_dpp(hi, hi, ctrl, rmask, 0xf, false);          \
    u64 sp = ((u64)shi << 32) | slo;                                                      \
    pk = sp > pk ? sp : pk;                                                               \
  }

// Packed fp32 (VOP3P) distance chain via inline asm: VALUBusy showed ~685
// wave-instr/step, i.e. the v2f ops were scalarized by the compiler. These 8
// pk-issues per m replace 16 scalar issues; per-component rounding is IEEE RN,
// order matches numpy ((dx*dx + dy*dy) + dz*dz) exactly (no FMA contraction).
#define FPS_DIST_PK(PX, PY, PZ, CX, CY, CZ, D)                                            \
  v2f dx_, dy_, dz_, xx_, yy_, zz_, s1_;                                                  \
  asm("v_pk_add_f32 %0, %1, %2 neg_lo:[0,1] neg_hi:[0,1]" : "=v"(dx_) : "v"(PX), "v"(CX));\
  asm("v_pk_add_f32 %0, %1, %2 neg_lo:[0,1] neg_hi:[0,1]" : "=v"(dy_) : "v"(PY), "v"(CY));\
  asm("v_pk_add_f32 %0, %1, %2 neg_lo:[0,1] neg_hi:[0,1]" : "=v"(dz_) : "v"(PZ), "v"(CZ));\
  asm("v_pk_mul_f32 %0, %1, %1" : "=v"(xx_) : "v"(dx_));                                  \
  asm("v_pk_mul_f32 %0, %1, %1" : "=v"(yy_) : "v"(dy_));                                  \
  asm("v_pk_mul_f32 %0, %1, %1" : "=v"(zz_) : "v"(dz_));                                  \
  asm("v_pk_add_f32 %0, %1, %2" : "=v"(s1_) : "v"(xx_), "v"(yy_));                        \
  asm("v_pk_add_f32 %0, %1, %2" : "=v"(D) : "v"(s1_), "v"(zz_));

__global__ __launch_bounds__(256)
__attribute__((amdgpu_waves_per_eu(1, 1)))
void fps_kernel(const float* __restrict__ xyz, float* __restrict__ newxyz) {
  const int b = blockIdx.x;
  const int t = threadIdx.x;
  const float* X = xyz + (size_t)b * NPT * 3;
  __shared__ float lx[NPT * 3];   // 96 KB xyz copy (winner-coord fetch by index)
  __shared__ float cent[NS * 3];  // 12 KB centroid buffer, dumped at the end
  __shared__ u64 warr[2][4];      // per-wave packed winner, parity-buffered
#pragma unroll
  for (int i = 0; i < (NPT * 3) / 256; ++i) lx[t + i * 256] = X[t + i * 256];

  v2f px[16], py[16], pz[16], dst[16];
#pragma unroll
  for (int m = 0; m < 16; ++m) {
    int p0 = t + m * 512;
    int p1 = t + m * 512 + 256;
    px[m] = (v2f){X[p0 * 3 + 0], X[p1 * 3 + 0]};
    py[m] = (v2f){X[p0 * 3 + 1], X[p1 * 3 + 1]};
    pz[m] = (v2f){X[p0 * 3 + 2], X[p1 * 3 + 2]};
    dst[m] = (v2f){1e10f, 1e10f};
  }
#pragma unroll
  for (int m = 0; m < 16; ++m) {
    asm volatile("" : "+v"(px[m]), "+v"(py[m]), "+v"(pz[m]));
  }
  float cx = X[0], cy = X[1], cz = X[2];
  __syncthreads();
  for (int s = 0; s < NS; ++s) {
    if (t == 0) {
      cent[s * 3 + 0] = cx; cent[s * 3 + 1] = cy; cent[s * 3 + 2] = cz;
    }
    float bv = -1.0f;
    int bj = 0;
    {
      const v2f cxv = {cx, cx}, cyv = {cy, cy}, czv = {cz, cz};
#pragma unroll
      for (int m = 0; m < 16; ++m) {
        v2f d;
        FPS_DIST_PK(px[m], py[m], pz[m], cxv, cyv, czv, d)
        float n0 = fminf(dst[m].x, d.x);
        float n1 = fminf(dst[m].y, d.y);
        dst[m].x = n0; dst[m].y = n1;
        // ascending global index order (j=2m then 2m+1); strict > keeps first max
        if (n0 > bv) { bv = n0; bj = 2 * m; }
        if (n1 > bv) { bv = n1; bj = 2 * m + 1; }
      }
    }
    const int bi = t | (bj << 8);  // == t + bj*256 = global point index
    u64 pk = ((u64)(unsigned)__float_as_int(bv) << 32) | (unsigned)~bi;
    FPS_DPP_STEP_PK(0x111, 0xf)  // row_shr:1
    FPS_DPP_STEP_PK(0x112, 0xf)  // row_shr:2
    FPS_DPP_STEP_PK(0x114, 0xf)  // row_shr:4
    FPS_DPP_STEP_PK(0x118, 0xf)  // row_shr:8
    FPS_DPP_STEP_PK(0x142, 0xa)  // row_bcast15
    FPS_DPP_STEP_PK(0x143, 0xc)  // row_bcast31 -> lane63 = wave winner
    const int par = s & 1;
    if ((t & 63) == 63) warr[par][t >> 6] = pk;
    __syncthreads();
    u64 w = warr[par][0];
    {
      u64 w1 = warr[par][1]; w = w1 > w ? w1 : w;
      u64 w2 = warr[par][2]; w = w2 > w ? w2 : w;
      u64 w3 = warr[par][3]; w = w3 > w ? w3 : w;
    }
    const int i0 = (int)(~(unsigned)w) & (NPT - 1);  // winner point index
    cx = lx[i0 * 3 + 0]; cy = lx[i0 * 3 + 1]; cz = lx[i0 * 3 + 2];
  }
  __syncthreads();
  float* ob = newxyz + (size_t)b * NS * 3;
#pragma unroll
  for (int i = 0; i < 12; ++i) ob[t + i * 256] = cent[t + i * 256];
}

// ---------------- Ball query + gather + concat -> x0^T (channel-major) ----------------
__global__ __launch_bounds__(256) void ballq_kernel(const float* __restrict__ xyz,
                                                    const float* __restrict__ pts,
                                                    const float* __restrict__ newxyz,
                                                    float* __restrict__ x0T) {
  const int wid = threadIdx.x >> 6;
  const int lane = threadIdx.x & 63;
  const int gw = blockIdx.x * 4 + wid;  // global center 0..8191
  const int b = gw >> 10;
  const float* X = xyz + (size_t)b * NPT * 3;
  const float cx = newxyz[gw * 3 + 0], cy = newxyz[gw * 3 + 1], cz = newxyz[gw * 3 + 2];
  const float r2 = (float)(0.2 * 0.2);
  const float s2c = __fadd_rn(__fadd_rn(__fmul_rn(cx, cx), __fmul_rn(cy, cy)), __fmul_rn(cz, cz));
  __shared__ int sel[4][NK];
  int cnt = 0;
  for (int chunk = 0; chunk < NPT / 64; ++chunk) {
    int p = chunk * 64 + lane;
    float x = X[p * 3 + 0], y = X[p * 3 + 1], z = X[p * 3 + 2];
    float s2p = __fadd_rn(__fadd_rn(__fmul_rn(x, x), __fmul_rn(y, y)), __fmul_rn(z, z));
    float dot = __fadd_rn(__fadd_rn(__fmul_rn(cx, x), __fmul_rn(cy, y)), __fmul_rn(cz, z));
    float sq = __fsub_rn(__fadd_rn(s2c, s2p), __fmul_rn(2.0f, dot));
    bool in = !(sq > r2);
    unsigned long long m = __ballot(in);
    if (in) {
      int slot = cnt + (int)__popcll(m & ((1ull << lane) - 1ull));
      if (slot < NK) sel[wid][slot] = p;
    }
    cnt += (int)__popcll(m);
    if (cnt >= NK) break;  // wave-uniform
  }
  __threadfence_block();
  int first = sel[wid][0];  // center itself always in-radius (sq == 0 exactly)
  if (cnt < NK) {
    for (int s = cnt + lane; s < NK; s += 64) sel[wid][s] = first;
  }
  __threadfence_block();
  if (lane < NK) {
    int p = sel[wid][lane];
    const float* f = pts + ((size_t)b * NPT + p) * 6;
    const size_t col = (size_t)gw * NK + lane;
    x0T[0 * (size_t)N + col] = f[0];
    x0T[1 * (size_t)N + col] = f[1];
    x0T[2 * (size_t)N + col] = f[2];
    x0T[3 * (size_t)N + col] = f[3];
    x0T[4 * (size_t)N + col] = f[4];
    x0T[5 * (size_t)N + col] = f[5];
    x0T[6 * (size_t)N + col] = X[p * 3 + 0] - cx;
    x0T[7 * (size_t)N + col] = X[p * 3 + 1] - cy;
    x0T[8 * (size_t)N + col] = X[p * 3 + 2] - cz;
  }
}

// ---------------- moments for C=9: per-thread upper-tri outer product ----------------
__device__ __forceinline__ constexpr int tri9(int i, int j) { return 9 * i - i * (i + 1) / 2 + j; }

// waves_per_eu(4,4): ~75 VGPR live (a45+sm+v) vs default 8-wave target's 64-cap
// -> spill. Budget 128 removes it (same allocator disease as fps r3-r6).
__global__ __launch_bounds__(256)
__attribute__((amdgpu_waves_per_eu(4, 4)))
void moments9_kernel(const float* __restrict__ xT, float* __restrict__ acc) {
  const int tid = threadIdx.x;
  const int lane = tid & 63, wid = tid >> 6;
  float a45[45];
  float sm[9];
#pragma unroll
  for (int q = 0; q < 45; ++q) a45[q] = 0.f;
#pragma unroll
  for (int c = 0; c < 9; ++c) sm[c] = 0.f;
  const int p0 = blockIdx.x * 1024 + tid;
  for (int k = 0; k < 4; ++k) {
    int p = p0 + k * 256;
    float v[9];
#pragma unroll
    for (int c = 0; c < 9; ++c) v[c] = xT[(size_t)c * N + p];
#pragma unroll
    for (int c = 0; c < 9; ++c) sm[c] += v[c];
#pragma unroll
    for (int i = 0; i < 9; ++i)
#pragma unroll
      for (int j = i; j < 9; ++j) a45[tri9(i, j)] = fmaf(v[i], v[j], a45[tri9(i, j)]);
  }
  __shared__ float red[4][54];
#pragma unroll
  for (int q = 0; q < 45; ++q) {
    float w = wave_sum63(a45[q]);
    if (lane == 63) red[wid][q] = w;
  }
#pragma unroll
  for (int c = 0; c < 9; ++c) {
    float w = wave_sum63(sm[c]);
    if (lane == 63) red[wid][45 + c] = w;
  }
  __syncthreads();
  if (tid < 54) {
    float tot = red[0][tid] + red[1][tid] + red[2][tid] + red[3][tid];
    if (tid < 45) {
      int i = 0, rem = tid;
      while (rem >= 9 - i) { rem -= 9 - i; ++i; }
      int j = i + rem;
      atomicAdd(&acc[9 + i * 9 + j], tot);
    } else {
      atomicAdd(&acc[tid - 45], tot);
    }
  }
}

// ---------------- moments for C=64: A^T A GEMM tile over point chunks ----------------
__global__ __launch_bounds__(256)
__attribute__((amdgpu_waves_per_eu(4, 4)))
void moments64_kernel(const float* __restrict__ xT, float* __restrict__ acc) {
  __shared__ float sm[32 * 68];  // [p][c] padded to 68
  const int tid = threadIdx.x;
  const int ti = (tid & 15) * 4;
  const int tj = (tid >> 4) * 4;
  float av[4][4];
#pragma unroll
  for (int i = 0; i < 4; ++i)
#pragma unroll
    for (int j = 0; j < 4; ++j) av[i][j] = 0.f;
  float s = 0.f;
  for (int ch = 0; ch < 16; ++ch) {
    const int p0 = blockIdx.x * 512 + ch * 32;
#pragma unroll
    for (int k = 0; k < 8; ++k) {
      int e = tid + k * 256;
      int c = e >> 5, pp = e & 31;
      sm[pp * 68 + c] = xT[(size_t)c * N + p0 + pp];
    }
    __syncthreads();
#pragma unroll
    for (int p = 0; p < 32; ++p) {
      float4 a = *reinterpret_cast<const float4*>(&sm[p * 68 + ti]);
      float4 bq = *reinterpret_cast<const float4*>(&sm[p * 68 + tj]);
      av[0][0] = fmaf(a.x, bq.x, av[0][0]); av[0][1] = fmaf(a.x, bq.y, av[0][1]);
      av[0][2] = fmaf(a.x, bq.z, av[0][2]); av[0][3] = fmaf(a.x, bq.w, av[0][3]);
      av[1][0] = fmaf(a.y, bq.x, av[1][0]); av[1][1] = fmaf(a.y, bq.y, av[1][1]);
      av[1][2] = fmaf(a.y, bq.z, av[1][2]); av[1][3] = fmaf(a.y, bq.w, av[1][3]);
      av[2][0] = fmaf(a.z, bq.x, av[2][0]); av[2][1] = fmaf(a.z, bq.y, av[2][1]);
      av[2][2] = fmaf(a.z, bq.z, av[2][2]); av[2][3] = fmaf(a.z, bq.w, av[2][3]);
      av[3][0] = fmaf(a.w, bq.x, av[3][0]); av[3][1] = fmaf(a.w, bq.y, av[3][1]);
      av[3][2] = fmaf(a.w, bq.z, av[3][2]); av[3][3] = fmaf(a.w, bq.w, av[3][3]);
    }
    if (tid < 64) {
#pragma unroll
      for (int p = 0; p < 32; ++p) s += sm[p * 68 + tid];
    }
    __syncthreads();
  }
#pragma unroll
  for (int i = 0; i < 4; ++i)
#pragma unroll
    for (int j = 0; j < 4; ++j) atomicAdd(&acc[64 + (ti + i) * 64 + (tj + j)], av[i][j]);
  if (tid < 64) atomicAdd(&acc[tid], s);
}

// ---------------- stats transform: analytic mean/var -> scale/shift ----------------
__global__ void xform1_kernel(const float* __restrict__ a, const float* __restrict__ W,
                              const float* __restrict__ bb, const float* __restrict__ g,
                              const float* __restrict__ be, float* __restrict__ sc,
                              float* __restrict__ sh) {
  const int d = threadIdx.x;  // 64
  const float invN = 1.0f / (float)N;
  float mu[9];
#pragma unroll
  for (int i = 0; i < 9; ++i) mu[i] = a[i] * invN;
  float m = bb[d];
#pragma unroll
  for (int i = 0; i < 9; ++i) m = fmaf(mu[i], W[i * 64 + d], m);
  float var = 0.f;
#pragma unroll
  for (int i = 0; i < 9; ++i) {
    float wi = W[i * 64 + d];
#pragma unroll
    for (int j = 0; j < 9; ++j) {
      float E = a[9 + (i <= j ? i * 9 + j : j * 9 + i)] * invN;
      float C = fmaf(-mu[i], mu[j], E);
      var = fmaf(wi * W[j * 64 + d], C, var);
    }
  }
  float s = g[d] / sqrtf(var + 1e-5f);
  sc[d] = s;
  sh[d] = fmaf(s, bb[d] - m, be[d]);
}

template <int COUT>
__global__ void xform64_kernel(const float* __restrict__ a, const float* __restrict__ W,
                               const float* __restrict__ bb, const float* __restrict__ g,
                               const float* __restrict__ be, float* __restrict__ sc,
                               float* __restrict__ sh) {
  constexpr int NQ = 256 / COUT;  // 4 (COUT=64) or 2 (COUT=128)
  constexpr int CH = 64 / NQ;
  __shared__ float smu[64];
  __shared__ float pvar[NQ][COUT];
  const int tid = threadIdx.x;
  const int d = tid % COUT;
  const int q = tid / COUT;
  const float invN = 1.0f / (float)N;
  if (tid < 64) smu[tid] = a[tid] * invN;
  __syncthreads();
  float var = 0.f;
  for (int i = q * CH; i < (q + 1) * CH; ++i) {
    float wi = W[i * COUT + d];
    float mi = smu[i];
    for (int j = 0; j < 64; ++j) {
      float C = fmaf(-mi, smu[j], a[64 + i * 64 + j] * invN);
      var = fmaf(wi * W[j * COUT + d], C, var);
    }
  }
  pvar[q][d] = var;
  __syncthreads();
  if (q == 0) {
    for (int k = 1; k < NQ; ++k) var += pvar[k][d];
    float m = bb[d];
    for (int i = 0; i < 64; ++i) m = fmaf(smu[i], W[i * COUT + d], m);
    float s = g[d] / sqrtf(var + 1e-5f);
    sc[d] = s;
    sh[d] = fmaf(s, bb[d] - m, be[d]);
  }
}

// ---------------- fused matmul + normalize + relu (thread-per-point) ----------------
// waves_per_eu(4,4): acc[COUT<=64] + addressing ~90 VGPR; default 8-wave target
// (64 cap) spilled the accumulator every inner iteration.
template <int CIN, int COUT>
__global__ __launch_bounds__(256)
__attribute__((amdgpu_waves_per_eu(4, 4)))
void mm_kernel(const float* __restrict__ xin,
               const float* __restrict__ W,
               const float* __restrict__ sc,
               const float* __restrict__ sh,
               float* __restrict__ xout) {
  const int p = blockIdx.x * 256 + threadIdx.x;
  float acc[COUT];
#pragma unroll
  for (int co = 0; co < COUT; ++co) acc[co] = 0.f;
  for (int ci = 0; ci < CIN; ++ci) {
    float xv = xin[(size_t)ci * N + p];
#pragma unroll
    for (int co = 0; co < COUT; ++co) acc[co] = fmaf(xv, W[ci * COUT + co], acc[co]);
  }
#pragma unroll
  for (int co = 0; co < COUT; ++co) {
    float v = fmaxf(0.f, fmaf(acc[co], sc[co], sh[co]));
    xout[(size_t)co * N + p] = v;
  }
}

// ---------------- final: matmul + normalize + relu + max over K (DPP) ----------------
#define DPPMAX(ctrl, rmask)                                                               \
  v = fmaxf(v, __int_as_float(__builtin_amdgcn_update_dpp(                                \
                  __float_as_int(v), __float_as_int(v), ctrl, rmask, 0xf, false)));

__global__ __launch_bounds__(256)
__attribute__((amdgpu_waves_per_eu(2, 2)))
void mm_final_kernel(const float* __restrict__ xin,
                     const float* __restrict__ W,
                     const float* __restrict__ sc,
                     const float* __restrict__ sh,
                     float* __restrict__ outp) {
  const int p = blockIdx.x * 256 + threadIdx.x;
  float acc[128];
#pragma unroll
  for (int co = 0; co < 128; ++co) acc[co] = 0.f;
  for (int ci = 0; ci < 64; ++ci) {
    float xv = xin[(size_t)ci * N + p];
#pragma unroll
    for (int co = 0; co < 128; ++co) acc[co] = fmaf(xv, W[ci * 128 + co], acc[co]);
  }
  const int c = p >> 5;
  const bool wlast = (threadIdx.x & 31) == 31;
#pragma unroll
  for (int co = 0; co < 128; ++co) {
    float v = fmaxf(0.f, fmaf(acc[co], sc[co], sh[co]));
    DPPMAX(0xB1, 0xf)   // quad_perm xor1
    DPPMAX(0x4E, 0xf)   // quad_perm xor2
    DPPMAX(0x124, 0xf)  // row_ror:4
    DPPMAX(0x128, 0xf)  // row_ror:8
    DPPMAX(0x142, 0xa)  // row_bcast15 -> lanes 31/63 cover their 32-group
    if (wlast) outp[(size_t)c * 128 + co] = v;
  }
}

extern "C" void kernel_launch(void* const* d_in, const int* in_sizes, int n_in,
                              void* d_out, int out_size, void* d_ws, size_t ws_size,
                              hipStream_t stream) {
  const float* xyz = (const float*)d_in[0];
  const float* pts = (const float*)d_in[1];
  const float* W0 = (const float*)d_in[2];
  const float* b0 = (const float*)d_in[3];
  const float* g0 = (const float*)d_in[4];
  const float* be0 = (const float*)d_in[5];
  const float* W1 = (const float*)d_in[6];
  const float* b1 = (const float*)d_in[7];
  const float* g1 = (const float*)d_in[8];
  const float* be1 = (const float*)d_in[9];
  const float* W2 = (const float*)d_in[10];
  const float* b2 = (const float*)d_in[11];
  const float* g2 = (const float*)d_in[12];
  const float* be2 = (const float*)d_in[13];

  float* out = (float*)d_out;
  float* newxyz = out;                // (B,S,3)
  float* outpts = out + NB * NS * 3;  // (B,S,128)

  float* ws = (float*)d_ws;
  float* x0T = ws;                      // 9N
  float* x1T = ws + (size_t)9 * N;      // 64N
  float* x2T = ws + (size_t)73 * N;     // 64N
  float* scsh = ws + (size_t)137 * N;   // 512 floats
  float* sc1 = scsh, *sh1 = scsh + 64;
  float* sc2 = scsh + 128, *sh2 = scsh + 192;
  float* sc3 = scsh + 256, *sh3 = scsh + 384;
  float* cov0 = x1T;  // 90 floats, consumed by xform1 before mm1 writes x1T
  float* cov1 = x2T;  // 4160 floats, consumed by xform2 before mm2 writes x2T
  float* cov2 = x0T;  // 4160 floats, written after x0T is dead (post-mm1)

  hipMemsetAsync(cov0, 0, 90 * sizeof(float), stream);
  hipMemsetAsync(cov1, 0, 4160 * sizeof(float), stream);

  fps_kernel<<<NB, 256, 0, stream>>>(xyz, newxyz);
  ballq_kernel<<<(NB * NS) / 4, 256, 0, stream>>>(xyz, pts, newxyz, x0T);

  moments9_kernel<<<256, 256, 0, stream>>>(x0T, cov0);
  xform1_kernel<<<1, 64, 0, stream>>>(cov0, W0, b0, g0, be0, sc1, sh1);
  mm_kernel<9, 64><<<N / 256, 256, 0, stream>>>(x0T, W0, sc1, sh1, x1T);

  moments64_kernel<<<512, 256, 0, stream>>>(x1T, cov1);
  xform64_kernel<64><<<1, 256, 0, stream>>>(cov1, W1, b1, g1, be1, sc2, sh2);
  mm_kernel<64, 64><<<N / 256, 256, 0, stream>>>(x1T, W1, sc2, sh2, x2T);

  hipMemsetAsync(cov2, 0, 4160 * sizeof(float), stream);
  moments64_kernel<<<512, 256, 0, stream>>>(x2T, cov2);
  xform64_kernel<128><<<1, 256, 0, stream>>>(cov2, W2, b2, g2, be2, sc3, sh3);
  mm_final_kernel<<<N / 256, 256, 0, stream>>>(x2T, W2, sc3, sh3, outpts);
}

// Round 10
// 1813.019 us; speedup vs baseline: 1.2902x; 1.2902x over previous
//
#include <hip/hip_runtime.h>
#include <cstdint>
#include <cstddef>

#define NB 8
#define NPT 8192
#define NS 1024
#define NK 32
static constexpr int N = NB * NS * NK;  // 262144 grouped points

typedef unsigned long long u64;

// ---------------- DPP helpers ----------------
// wave64 sum-reduce; valid result in lane 63 only.
__device__ __forceinline__ float wave_sum63(float v) {
  v += __int_as_float(__builtin_amdgcn_update_dpp(0, __float_as_int(v), 0x111, 0xf, 0xf, true));
  v += __int_as_float(__builtin_amdgcn_update_dpp(0, __float_as_int(v), 0x112, 0xf, 0xf, true));
  v += __int_as_float(__builtin_amdgcn_update_dpp(0, __float_as_int(v), 0x114, 0xf, 0xf, true));
  v += __int_as_float(__builtin_amdgcn_update_dpp(0, __float_as_int(v), 0x118, 0xf, 0xf, true));
  v += __int_as_float(__builtin_amdgcn_update_dpp(0, __float_as_int(v), 0x142, 0xa, 0xf, true));
  v += __int_as_float(__builtin_amdgcn_update_dpp(0, __float_as_int(v), 0x143, 0xc, 0xf, true));
  return v;
}

// ---------------- FPS: packed-u64 DPP argmax, coords fetched from LDS ----------------
// pk = (float_bits(bv) << 32) | ~bi : distances >= 0 so float bits are monotone
// as u32; for equal bv, larger ~bi = smaller index (numpy first-max tie-break).
#define FPS_DPP_STEP_PK(ctrl, rmask)                                                      \
  {                                                                                       \
    unsigned lo = (unsigned)pk, hi = (unsigned)(pk >> 32);                                \
    unsigned slo = __builtin_amdgcn_update_dpp(lo, lo, ctrl, rmask, 0xf, false);          \
    unsigned shi = __builtin_amdgcn_update_dpp(hi, hi, ctrl, rmask, 0xf, false);          \
    u64 sp = ((u64)shi << 32) | slo;                                                      \
    pk = sp > pk ? sp : pk;                                                               \
  }

// 256 thr x 32 pts, 1 wave/SIMD (wpe(1,1): 512-VGPR budget, no remat pressure).
// Inner loop: value-only max chain (1 op/pt) + post-hoc DESCENDING equality
// scan for the first-max index (2 ops/pt) — replaces the 6-op/pair inline
// (cmp, 2x cndmask) tracking and all v2f insert/extract churn of r8/r9.
__global__ __launch_bounds__(256)
__attribute__((amdgpu_waves_per_eu(1, 1)))
void fps_kernel(const float* __restrict__ xyz, float* __restrict__ newxyz) {
  const int b = blockIdx.x;
  const int t = threadIdx.x;
  const float* X = xyz + (size_t)b * NPT * 3;
  __shared__ float lx[NPT * 3];   // 96 KB xyz copy (winner-coord fetch by index)
  __shared__ float cent[NS * 3];  // 12 KB centroid buffer, dumped at the end
  __shared__ u64 warr[2][4];      // per-wave packed winner, parity-buffered
#pragma unroll
  for (int i = 0; i < (NPT * 3) / 256; ++i) lx[t + i * 256] = X[t + i * 256];

  float px[32], py[32], pz[32], dst[32];
#pragma unroll
  for (int j = 0; j < 32; ++j) {
    int p = t + j * 256;
    px[j] = X[p * 3 + 0];
    py[j] = X[p * 3 + 1];
    pz[j] = X[p * 3 + 2];
    dst[j] = 1e10f;
  }
  // Keep coords opaque to rematerialization (r3-r6: without this the allocator
  // rematerialized the loads inside the step loop).
#pragma unroll
  for (int j = 0; j < 32; ++j) {
    asm volatile("" : "+v"(px[j]), "+v"(py[j]), "+v"(pz[j]));
  }
  float cx = X[0], cy = X[1], cz = X[2];
  __syncthreads();
  for (int s = 0; s < NS; ++s) {
    if (t == 0) {
      cent[s * 3 + 0] = cx; cent[s * 3 + 1] = cy; cent[s * 3 + 2] = cz;
    }
    float bv = -1.0f;
    {
#pragma unroll
      for (int j = 0; j < 32; ++j) {
        // exact numpy order: ((dx*dx + dy*dy) + dz*dz), explicit RN ops
        float dx = __fsub_rn(px[j], cx);
        float dy = __fsub_rn(py[j], cy);
        float dz = __fsub_rn(pz[j], cz);
        float d = __fadd_rn(__fadd_rn(__fmul_rn(dx, dx), __fmul_rn(dy, dy)), __fmul_rn(dz, dz));
        float nd = fminf(dst[j], d);
        dst[j] = nd;
        bv = fmaxf(bv, nd);
      }
    }
    // descending scan: final bj = SMALLEST j with dst[j]==bv (first-max)
    int bj = 0;
#pragma unroll
    for (int j = 31; j >= 0; --j) {
      if (dst[j] == bv) bj = j;
    }
    const int bi = t | (bj << 8);  // global point index (t<256, j<32)
    u64 pk = ((u64)(unsigned)__float_as_int(bv) << 32) | (unsigned)~bi;
    FPS_DPP_STEP_PK(0x111, 0xf)  // row_shr:1
    FPS_DPP_STEP_PK(0x112, 0xf)  // row_shr:2
    FPS_DPP_STEP_PK(0x114, 0xf)  // row_shr:4
    FPS_DPP_STEP_PK(0x118, 0xf)  // row_shr:8
    FPS_DPP_STEP_PK(0x142, 0xa)  // row_bcast15
    FPS_DPP_STEP_PK(0x143, 0xc)  // row_bcast31 -> lane63 = wave winner
    const int par = s & 1;
    if ((t & 63) == 63) warr[par][t >> 6] = pk;
    __syncthreads();
    u64 w = warr[par][0];
    {
      u64 w1 = warr[par][1]; w = w1 > w ? w1 : w;
      u64 w2 = warr[par][2]; w = w2 > w ? w2 : w;
      u64 w3 = warr[par][3]; w = w3 > w ? w3 : w;
    }
    const int i0 = (int)(~(unsigned)w) & (NPT - 1);  // winner point index
    cx = lx[i0 * 3 + 0]; cy = lx[i0 * 3 + 1]; cz = lx[i0 * 3 + 2];
  }
  __syncthreads();
  float* ob = newxyz + (size_t)b * NS * 3;
#pragma unroll
  for (int i = 0; i < 12; ++i) ob[t + i * 256] = cent[t + i * 256];
}

// ---------------- Ball query + gather + concat -> x0^T (channel-major) ----------------
__global__ __launch_bounds__(256) void ballq_kernel(const float* __restrict__ xyz,
                                                    const float* __restrict__ pts,
                                                    const float* __restrict__ newxyz,
                                                    float* __restrict__ x0T) {
  const int wid = threadIdx.x >> 6;
  const int lane = threadIdx.x & 63;
  const int gw = blockIdx.x * 4 + wid;  // global center 0..8191
  const int b = gw >> 10;
  const float* X = xyz + (size_t)b * NPT * 3;
  const float cx = newxyz[gw * 3 + 0], cy = newxyz[gw * 3 + 1], cz = newxyz[gw * 3 + 2];
  const float r2 = (float)(0.2 * 0.2);
  const float s2c = __fadd_rn(__fadd_rn(__fmul_rn(cx, cx), __fmul_rn(cy, cy)), __fmul_rn(cz, cz));
  __shared__ int sel[4][NK];
  int cnt = 0;
  for (int chunk = 0; chunk < NPT / 64; ++chunk) {
    int p = chunk * 64 + lane;
    float x = X[p * 3 + 0], y = X[p * 3 + 1], z = X[p * 3 + 2];
    float s2p = __fadd_rn(__fadd_rn(__fmul_rn(x, x), __fmul_rn(y, y)), __fmul_rn(z, z));
    float dot = __fadd_rn(__fadd_rn(__fmul_rn(cx, x), __fmul_rn(cy, y)), __fmul_rn(cz, z));
    float sq = __fsub_rn(__fadd_rn(s2c, s2p), __fmul_rn(2.0f, dot));
    bool in = !(sq > r2);
    unsigned long long m = __ballot(in);
    if (in) {
      int slot = cnt + (int)__popcll(m & ((1ull << lane) - 1ull));
      if (slot < NK) sel[wid][slot] = p;
    }
    cnt += (int)__popcll(m);
    if (cnt >= NK) break;  // wave-uniform
  }
  __threadfence_block();
  int first = sel[wid][0];  // center itself always in-radius (sq == 0 exactly)
  if (cnt < NK) {
    for (int s = cnt + lane; s < NK; s += 64) sel[wid][s] = first;
  }
  __threadfence_block();
  if (lane < NK) {
    int p = sel[wid][lane];
    const float* f = pts + ((size_t)b * NPT + p) * 6;
    const size_t col = (size_t)gw * NK + lane;
    x0T[0 * (size_t)N + col] = f[0];
    x0T[1 * (size_t)N + col] = f[1];
    x0T[2 * (size_t)N + col] = f[2];
    x0T[3 * (size_t)N + col] = f[3];
    x0T[4 * (size_t)N + col] = f[4];
    x0T[5 * (size_t)N + col] = f[5];
    x0T[6 * (size_t)N + col] = X[p * 3 + 0] - cx;
    x0T[7 * (size_t)N + col] = X[p * 3 + 1] - cy;
    x0T[8 * (size_t)N + col] = X[p * 3 + 2] - cz;
  }
}

// ---------------- moments for C=9: per-thread upper-tri outer product ----------------
__device__ __forceinline__ constexpr int tri9(int i, int j) { return 9 * i - i * (i + 1) / 2 + j; }

__global__ __launch_bounds__(256) void moments9_kernel(const float* __restrict__ xT,
                                                       float* __restrict__ acc) {
  const int tid = threadIdx.x;
  const int lane = tid & 63, wid = tid >> 6;
  float a45[45];
  float sm[9];
#pragma unroll
  for (int q = 0; q < 45; ++q) a45[q] = 0.f;
#pragma unroll
  for (int c = 0; c < 9; ++c) sm[c] = 0.f;
  const int p0 = blockIdx.x * 1024 + tid;
  for (int k = 0; k < 4; ++k) {
    int p = p0 + k * 256;
    float v[9];
#pragma unroll
    for (int c = 0; c < 9; ++c) v[c] = xT[(size_t)c * N + p];
#pragma unroll
    for (int c = 0; c < 9; ++c) sm[c] += v[c];
#pragma unroll
    for (int i = 0; i < 9; ++i)
#pragma unroll
      for (int j = i; j < 9; ++j) a45[tri9(i, j)] = fmaf(v[i], v[j], a45[tri9(i, j)]);
  }
  __shared__ float red[4][54];
#pragma unroll
  for (int q = 0; q < 45; ++q) {
    float w = wave_sum63(a45[q]);
    if (lane == 63) red[wid][q] = w;
  }
#pragma unroll
  for (int c = 0; c < 9; ++c) {
    float w = wave_sum63(sm[c]);
    if (lane == 63) red[wid][45 + c] = w;
  }
  __syncthreads();
  if (tid < 54) {
    float tot = red[0][tid] + red[1][tid] + red[2][tid] + red[3][tid];
    if (tid < 45) {
      int i = 0, rem = tid;
      while (rem >= 9 - i) { rem -= 9 - i; ++i; }
      int j = i + rem;
      atomicAdd(&acc[9 + i * 9 + j], tot);
    } else {
      atomicAdd(&acc[tid - 45], tot);
    }
  }
}

// ---------------- moments for C=64: A^T A GEMM tile over point chunks ----------------
__global__ __launch_bounds__(256) void moments64_kernel(const float* __restrict__ xT,
                                                        float* __restrict__ acc) {
  __shared__ float sm[32 * 68];  // [p][c] padded to 68
  const int tid = threadIdx.x;
  const int ti = (tid & 15) * 4;
  const int tj = (tid >> 4) * 4;
  float av[4][4];
#pragma unroll
  for (int i = 0; i < 4; ++i)
#pragma unroll
    for (int j = 0; j < 4; ++j) av[i][j] = 0.f;
  float s = 0.f;
  for (int ch = 0; ch < 16; ++ch) {
    const int p0 = blockIdx.x * 512 + ch * 32;
#pragma unroll
    for (int k = 0; k < 8; ++k) {
      int e = tid + k * 256;
      int c = e >> 5, pp = e & 31;
      sm[pp * 68 + c] = xT[(size_t)c * N + p0 + pp];
    }
    __syncthreads();
#pragma unroll
    for (int p = 0; p < 32; ++p) {
      float4 a = *reinterpret_cast<const float4*>(&sm[p * 68 + ti]);
      float4 bq = *reinterpret_cast<const float4*>(&sm[p * 68 + tj]);
      av[0][0] = fmaf(a.x, bq.x, av[0][0]); av[0][1] = fmaf(a.x, bq.y, av[0][1]);
      av[0][2] = fmaf(a.x, bq.z, av[0][2]); av[0][3] = fmaf(a.x, bq.w, av[0][3]);
      av[1][0] = fmaf(a.y, bq.x, av[1][0]); av[1][1] = fmaf(a.y, bq.y, av[1][1]);
      av[1][2] = fmaf(a.y, bq.z, av[1][2]); av[1][3] = fmaf(a.y, bq.w, av[1][3]);
      av[2][0] = fmaf(a.z, bq.x, av[2][0]); av[2][1] = fmaf(a.z, bq.y, av[2][1]);
      av[2][2] = fmaf(a.z, bq.z, av[2][2]); av[2][3] = fmaf(a.z, bq.w, av[2][3]);
      av[3][0] = fmaf(a.w, bq.x, av[3][0]); av[3][1] = fmaf(a.w, bq.y, av[3][1]);
      av[3][2] = fmaf(a.w, bq.z, av[3][2]); av[3][3] = fmaf(a.w, bq.w, av[3][3]);
    }
    if (tid < 64) {
#pragma unroll
      for (int p = 0; p < 32; ++p) s += sm[p * 68 + tid];
    }
    __syncthreads();
  }
#pragma unroll
  for (int i = 0; i < 4; ++i)
#pragma unroll
    for (int j = 0; j < 4; ++j) atomicAdd(&acc[64 + (ti + i) * 64 + (tj + j)], av[i][j]);
  if (tid < 64) atomicAdd(&acc[tid], s);
}

// ---------------- stats transform: analytic mean/var -> scale/shift ----------------
__global__ void xform1_kernel(const float* __restrict__ a, const float* __restrict__ W,
                              const float* __restrict__ bb, const float* __restrict__ g,
                              const float* __restrict__ be, float* __restrict__ sc,
                              float* __restrict__ sh) {
  const int d = threadIdx.x;  // 64
  const float invN = 1.0f / (float)N;
  float mu[9];
#pragma unroll
  for (int i = 0; i < 9; ++i) mu[i] = a[i] * invN;
  float m = bb[d];
#pragma unroll
  for (int i = 0; i < 9; ++i) m = fmaf(mu[i], W[i * 64 + d], m);
  float var = 0.f;
#pragma unroll
  for (int i = 0; i < 9; ++i) {
    float wi = W[i * 64 + d];
#pragma unroll
    for (int j = 0; j < 9; ++j) {
      float E = a[9 + (i <= j ? i * 9 + j : j * 9 + i)] * invN;
      float C = fmaf(-mu[i], mu[j], E);
      var = fmaf(wi * W[j * 64 + d], C, var);
    }
  }
  float s = g[d] / sqrtf(var + 1e-5f);
  sc[d] = s;
  sh[d] = fmaf(s, bb[d] - m, be[d]);
}

template <int COUT>
__global__ void xform64_kernel(const float* __restrict__ a, const float* __restrict__ W,
                               const float* __restrict__ bb, const float* __restrict__ g,
                               const float* __restrict__ be, float* __restrict__ sc,
                               float* __restrict__ sh) {
  constexpr int NQ = 256 / COUT;  // 4 (COUT=64) or 2 (COUT=128)
  constexpr int CH = 64 / NQ;
  __shared__ float smu[64];
  __shared__ float pvar[NQ][COUT];
  const int tid = threadIdx.x;
  const int d = tid % COUT;
  const int q = tid / COUT;
  const float invN = 1.0f / (float)N;
  if (tid < 64) smu[tid] = a[tid] * invN;
  __syncthreads();
  float var = 0.f;
  for (int i = q * CH; i < (q + 1) * CH; ++i) {
    float wi = W[i * COUT + d];
    float mi = smu[i];
    for (int j = 0; j < 64; ++j) {
      float C = fmaf(-mi, smu[j], a[64 + i * 64 + j] * invN);
      var = fmaf(wi * W[j * COUT + d], C, var);
    }
  }
  pvar[q][d] = var;
  __syncthreads();
  if (q == 0) {
    for (int k = 1; k < NQ; ++k) var += pvar[k][d];
    float m = bb[d];
    for (int i = 0; i < 64; ++i) m = fmaf(smu[i], W[i * COUT + d], m);
    float s = g[d] / sqrtf(var + 1e-5f);
    sc[d] = s;
    sh[d] = fmaf(s, bb[d] - m, be[d]);
  }
}

// ---------------- fused matmul + normalize + relu (thread-per-point) ----------------
template <int CIN, int COUT>
__global__ __launch_bounds__(256) void mm_kernel(const float* __restrict__ xin,
                                                 const float* __restrict__ W,
                                                 const float* __restrict__ sc,
                                                 const float* __restrict__ sh,
                                                 float* __restrict__ xout) {
  const int p = blockIdx.x * 256 + threadIdx.x;
  float acc[COUT];
#pragma unroll
  for (int co = 0; co < COUT; ++co) acc[co] = 0.f;
  for (int ci = 0; ci < CIN; ++ci) {
    float xv = xin[(size_t)ci * N + p];
#pragma unroll
    for (int co = 0; co < COUT; ++co) acc[co] = fmaf(xv, W[ci * COUT + co], acc[co]);
  }
#pragma unroll
  for (int co = 0; co < COUT; ++co) {
    float v = fmaxf(0.f, fmaf(acc[co], sc[co], sh[co]));
    xout[(size_t)co * N + p] = v;
  }
}

// ---------------- final: matmul + normalize + relu + max over K (DPP) ----------------
#define DPPMAX(ctrl, rmask)                                                               \
  v = fmaxf(v, __int_as_float(__builtin_amdgcn_update_dpp(                                \
                  __float_as_int(v), __float_as_int(v), ctrl, rmask, 0xf, false)));

__global__ __launch_bounds__(256)
__attribute__((amdgpu_waves_per_eu(2, 2)))
void mm_final_kernel(const float* __restrict__ xin,
                     const float* __restrict__ W,
                     const float* __restrict__ sc,
                     const float* __restrict__ sh,
                     float* __restrict__ outp) {
  const int p = blockIdx.x * 256 + threadIdx.x;
  float acc[128];
#pragma unroll
  for (int co = 0; co < 128; ++co) acc[co] = 0.f;
  for (int ci = 0; ci < 64; ++ci) {
    float xv = xin[(size_t)ci * N + p];
#pragma unroll
    for (int co = 0; co < 128; ++co) acc[co] = fmaf(xv, W[ci * 128 + co], acc[co]);
  }
  const int c = p >> 5;
  const bool wlast = (threadIdx.x & 31) == 31;
#pragma unroll
  for (int co = 0; co < 128; ++co) {
    float v = fmaxf(0.f, fmaf(acc[co], sc[co], sh[co]));
    DPPMAX(0xB1, 0xf)   // quad_perm xor1
    DPPMAX(0x4E, 0xf)   // quad_perm xor2
    DPPMAX(0x124, 0xf)  // row_ror:4
    DPPMAX(0x128, 0xf)  // row_ror:8
    DPPMAX(0x142, 0xa)  // row_bcast15 -> lanes 31/63 cover their 32-group
    if (wlast) outp[(size_t)c * 128 + co] = v;
  }
}

extern "C" void kernel_launch(void* const* d_in, const int* in_sizes, int n_in,
                              void* d_out, int out_size, void* d_ws, size_t ws_size,
                              hipStream_t stream) {
  const float* xyz = (const float*)d_in[0];
  const float* pts = (const float*)d_in[1];
  const float* W0 = (const float*)d_in[2];
  const float* b0 = (const float*)d_in[3];
  const float* g0 = (const float*)d_in[4];
  const float* be0 = (const float*)d_in[5];
  const float* W1 = (const float*)d_in[6];
  const float* b1 = (const float*)d_in[7];
  const float* g1 = (const float*)d_in[8];
  const float* be1 = (const float*)d_in[9];
  const float* W2 = (const float*)d_in[10];
  const float* b2 = (const float*)d_in[11];
  const float* g2 = (const float*)d_in[12];
  const float* be2 = (const float*)d_in[13];

  float* out = (float*)d_out;
  float* newxyz = out;                // (B,S,3)
  float* outpts = out + NB * NS * 3;  // (B,S,128)

  float* ws = (float*)d_ws;
  float* x0T = ws;                      // 9N
  float* x1T = ws + (size_t)9 * N;      // 64N
  float* x2T = ws + (size_t)73 * N;     // 64N
  float* scsh = ws + (size_t)137 * N;   // 512 floats
  float* sc1 = scsh, *sh1 = scsh + 64;
  float* sc2 = scsh + 128, *sh2 = scsh + 192;
  float* sc3 = scsh + 256, *sh3 = scsh + 384;
  float* cov0 = x1T;  // 90 floats, consumed by xform1 before mm1 writes x1T
  float* cov1 = x2T;  // 4160 floats, consumed by xform2 before mm2 writes x2T
  float* cov2 = x0T;  // 4160 floats, written after x0T is dead (post-mm1)

  hipMemsetAsync(cov0, 0, 90 * sizeof(float), stream);
  hipMemsetAsync(cov1, 0, 4160 * sizeof(float), stream);

  fps_kernel<<<NB, 256, 0, stream>>>(xyz, newxyz);
  ballq_kernel<<<(NB * NS) / 4, 256, 0, stream>>>(xyz, pts, newxyz, x0T);

  moments9_kernel<<<256, 256, 0, stream>>>(x0T, cov0);
  xform1_kernel<<<1, 64, 0, stream>>>(cov0, W0, b0, g0, be0, sc1, sh1);
  mm_kernel<9, 64><<<N / 256, 256, 0, stream>>>(x0T, W0, sc1, sh1, x1T);

  moments64_kernel<<<512, 256, 0, stream>>>(x1T, cov1);
  xform64_kernel<64><<<1, 256, 0, stream>>>(cov1, W1, b1, g1, be1, sc2, sh2);
  mm_kernel<64, 64><<<N / 256, 256, 0, stream>>>(x1T, W1, sc2, sh2, x2T);

  hipMemsetAsync(cov2, 0, 4160 * sizeof(float), stream);
  moments64_kernel<<<512, 256, 0, stream>>>(x2T, cov2);
  xform64_kernel<128><<<1, 256, 0, stream>>>(cov2, W2, b2, g2, be2, sc3, sh3);
  mm_final_kernel<<<N / 256, 256, 0, stream>>>(x2T, W2, sc3, sh3, outpts);
}

// Round 11
// 1764.383 us; speedup vs baseline: 1.3257x; 1.0276x over previous
//
#include <hip/hip_runtime.h>
#include <cstdint>
#include <cstddef>

#define NB 8
#define NPT 8192
#define NS 1024
#define NK 32
static constexpr int N = NB * NS * NK;  // 262144 grouped points

typedef float v2f __attribute__((ext_vector_type(2)));
typedef unsigned long long u64;

// ---------------- DPP helpers ----------------
// wave64 sum-reduce; valid result in lane 63 only.
__device__ __forceinline__ float wave_sum63(float v) {
  v += __int_as_float(__builtin_amdgcn_update_dpp(0, __float_as_int(v), 0x111, 0xf, 0xf, true));
  v += __int_as_float(__builtin_amdgcn_update_dpp(0, __float_as_int(v), 0x112, 0xf, 0xf, true));
  v += __int_as_float(__builtin_amdgcn_update_dpp(0, __float_as_int(v), 0x114, 0xf, 0xf, true));
  v += __int_as_float(__builtin_amdgcn_update_dpp(0, __float_as_int(v), 0x118, 0xf, 0xf, true));
  v += __int_as_float(__builtin_amdgcn_update_dpp(0, __float_as_int(v), 0x142, 0xa, 0xf, true));
  v += __int_as_float(__builtin_amdgcn_update_dpp(0, __float_as_int(v), 0x143, 0xc, 0xf, true));
  return v;
}

// ---------------- FPS: packed-u64 DPP argmax, coords fetched from LDS ----------------
// pk = (float_bits(bv) << 32) | ~bi : distances >= 0 so float bits are monotone
// as u32; for equal bv, larger ~bi = smaller index (numpy first-max tie-break).
#define FPS_DPP_STEP_PK(ctrl, rmask)                                                      \
  {                                                                                       \
    unsigned lo = (unsigned)pk, hi = (unsigned)(pk >> 32);                                \
    unsigned slo = __builtin_amdgcn_update_dpp(lo, lo, ctrl, rmask, 0xf, false);          \
    unsigned shi = __builtin_amdgcn_update_dpp(hi, hi, ctrl, rmask, 0xf, false);          \
    u64 sp = ((u64)shi << 32) | slo;                                                      \
    pk = sp > pk ? sp : pk;                                                               \
  }

// 512 thr x 16 pts: point arrays = 64 VGPRs (r8's 256x32 put 128 floats of
// state in a 132-VGPR allocation -> AGPR shuffling on every array access).
// wpe(2,2): 2 waves/SIMD, 256-VGPR budget, no occupancy-chasing remat.
__global__ __launch_bounds__(512)
__attribute__((amdgpu_waves_per_eu(2, 2)))
void fps_kernel(const float* __restrict__ xyz, float* __restrict__ newxyz) {
  const int b = blockIdx.x;
  const int t = threadIdx.x;
  const float* X = xyz + (size_t)b * NPT * 3;
  __shared__ float lx[NPT * 3];   // 96 KB xyz copy (winner-coord fetch by index)
  __shared__ float cent[NS * 3];  // 12 KB centroid buffer, dumped at the end
  __shared__ u64 warr[2][8];      // per-wave packed winner, parity-buffered
#pragma unroll
  for (int i = 0; i < (NPT * 3) / 512; ++i) lx[t + i * 512] = X[t + i * 512];

  v2f px[8], py[8], pz[8], dst[8];
#pragma unroll
  for (int m = 0; m < 8; ++m) {
    int p0 = t + (2 * m) * 512;
    int p1 = t + (2 * m + 1) * 512;
    px[m] = (v2f){X[p0 * 3 + 0], X[p1 * 3 + 0]};
    py[m] = (v2f){X[p0 * 3 + 1], X[p1 * 3 + 1]};
    pz[m] = (v2f){X[p0 * 3 + 2], X[p1 * 3 + 2]};
    dst[m] = (v2f){1e10f, 1e10f};
  }
  // Keep coords opaque to rematerialization (r3-r6 lesson).
#pragma unroll
  for (int m = 0; m < 8; ++m) {
    asm volatile("" : "+v"(px[m]), "+v"(py[m]), "+v"(pz[m]));
  }
  float cx = X[0], cy = X[1], cz = X[2];
  __syncthreads();
  for (int s = 0; s < NS; ++s) {
    if (t == 0) {
      cent[s * 3 + 0] = cx; cent[s * 3 + 1] = cy; cent[s * 3 + 2] = cz;
    }
    float bv = -1.0f;
    int bj = 0;
    {
#pragma clang fp contract(off)
      // per-component rounding identical to scalar RN; contract(off) forbids
      // FMA fusing so order matches numpy: ((dx*dx + dy*dy) + dz*dz)
      const v2f cxv = {cx, cx}, cyv = {cy, cy}, czv = {cz, cz};
#pragma unroll
      for (int m = 0; m < 8; ++m) {
        v2f dx = px[m] - cxv;
        v2f dy = py[m] - cyv;
        v2f dz = pz[m] - czv;
        v2f d = (dx * dx + dy * dy) + dz * dz;
        v2f nd = __builtin_elementwise_min(dst[m], d);
        dst[m] = nd;
        // ascending global index order (j=2m then 2m+1); strict > keeps first max
        if (nd.x > bv) { bv = nd.x; bj = 2 * m; }
        if (nd.y > bv) { bv = nd.y; bj = 2 * m + 1; }
      }
    }
    const int bi = t | (bj << 9);  // == t + bj*512 = global point index (t<512)
    u64 pk = ((u64)(unsigned)__float_as_int(bv) << 32) | (unsigned)~bi;
    FPS_DPP_STEP_PK(0x111, 0xf)  // row_shr:1
    FPS_DPP_STEP_PK(0x112, 0xf)  // row_shr:2
    FPS_DPP_STEP_PK(0x114, 0xf)  // row_shr:4
    FPS_DPP_STEP_PK(0x118, 0xf)  // row_shr:8
    FPS_DPP_STEP_PK(0x142, 0xa)  // row_bcast15
    FPS_DPP_STEP_PK(0x143, 0xc)  // row_bcast31 -> lane63 = wave winner
    const int par = s & 1;
    if ((t & 63) == 63) warr[par][t >> 6] = pk;
    __syncthreads();
    u64 w = warr[par][0];
#pragma unroll
    for (int k = 1; k < 8; ++k) {
      u64 wk = warr[par][k];
      w = wk > w ? wk : w;
    }
    const int i0 = (int)(~(unsigned)w) & (NPT - 1);  // winner point index
    cx = lx[i0 * 3 + 0]; cy = lx[i0 * 3 + 1]; cz = lx[i0 * 3 + 2];
  }
  __syncthreads();
  float* ob = newxyz + (size_t)b * NS * 3;
#pragma unroll
  for (int i = 0; i < 6; ++i) ob[t + i * 512] = cent[t + i * 512];
}

// ---------------- Ball query + gather + concat -> x0^T (channel-major) ----------------
__global__ __launch_bounds__(256) void ballq_kernel(const float* __restrict__ xyz,
                                                    const float* __restrict__ pts,
                                                    const float* __restrict__ newxyz,
                                                    float* __restrict__ x0T) {
  const int wid = threadIdx.x >> 6;
  const int lane = threadIdx.x & 63;
  const int gw = blockIdx.x * 4 + wid;  // global center 0..8191
  const int b = gw >> 10;
  const float* X = xyz + (size_t)b * NPT * 3;
  const float cx = newxyz[gw * 3 + 0], cy = newxyz[gw * 3 + 1], cz = newxyz[gw * 3 + 2];
  const float r2 = (float)(0.2 * 0.2);
  const float s2c = __fadd_rn(__fadd_rn(__fmul_rn(cx, cx), __fmul_rn(cy, cy)), __fmul_rn(cz, cz));
  __shared__ int sel[4][NK];
  int cnt = 0;
  for (int chunk = 0; chunk < NPT / 64; ++chunk) {
    int p = chunk * 64 + lane;
    float x = X[p * 3 + 0], y = X[p * 3 + 1], z = X[p * 3 + 2];
    float s2p = __fadd_rn(__fadd_rn(__fmul_rn(x, x), __fmul_rn(y, y)), __fmul_rn(z, z));
    float dot = __fadd_rn(__fadd_rn(__fmul_rn(cx, x), __fmul_rn(cy, y)), __fmul_rn(cz, z));
    float sq = __fsub_rn(__fadd_rn(s2c, s2p), __fmul_rn(2.0f, dot));
    bool in = !(sq > r2);
    unsigned long long m = __ballot(in);
    if (in) {
      int slot = cnt + (int)__popcll(m & ((1ull << lane) - 1ull));
      if (slot < NK) sel[wid][slot] = p;
    }
    cnt += (int)__popcll(m);
    if (cnt >= NK) break;  // wave-uniform
  }
  __threadfence_block();
  int first = sel[wid][0];  // center itself always in-radius (sq == 0 exactly)
  if (cnt < NK) {
    for (int s = cnt + lane; s < NK; s += 64) sel[wid][s] = first;
  }
  __threadfence_block();
  if (lane < NK) {
    int p = sel[wid][lane];
    const float* f = pts + ((size_t)b * NPT + p) * 6;
    const size_t col = (size_t)gw * NK + lane;
    x0T[0 * (size_t)N + col] = f[0];
    x0T[1 * (size_t)N + col] = f[1];
    x0T[2 * (size_t)N + col] = f[2];
    x0T[3 * (size_t)N + col] = f[3];
    x0T[4 * (size_t)N + col] = f[4];
    x0T[5 * (size_t)N + col] = f[5];
    x0T[6 * (size_t)N + col] = X[p * 3 + 0] - cx;
    x0T[7 * (size_t)N + col] = X[p * 3 + 1] - cy;
    x0T[8 * (size_t)N + col] = X[p * 3 + 2] - cz;
  }
}

// ---------------- moments for C=9: per-thread upper-tri outer product ----------------
__device__ __forceinline__ constexpr int tri9(int i, int j) { return 9 * i - i * (i + 1) / 2 + j; }

__global__ __launch_bounds__(256) void moments9_kernel(const float* __restrict__ xT,
                                                       float* __restrict__ acc) {
  const int tid = threadIdx.x;
  const int lane = tid & 63, wid = tid >> 6;
  float a45[45];
  float sm[9];
#pragma unroll
  for (int q = 0; q < 45; ++q) a45[q] = 0.f;
#pragma unroll
  for (int c = 0; c < 9; ++c) sm[c] = 0.f;
  const int p0 = blockIdx.x * 1024 + tid;
  for (int k = 0; k < 4; ++k) {
    int p = p0 + k * 256;
    float v[9];
#pragma unroll
    for (int c = 0; c < 9; ++c) v[c] = xT[(size_t)c * N + p];
#pragma unroll
    for (int c = 0; c < 9; ++c) sm[c] += v[c];
#pragma unroll
    for (int i = 0; i < 9; ++i)
#pragma unroll
      for (int j = i; j < 9; ++j) a45[tri9(i, j)] = fmaf(v[i], v[j], a45[tri9(i, j)]);
  }
  __shared__ float red[4][54];
#pragma unroll
  for (int q = 0; q < 45; ++q) {
    float w = wave_sum63(a45[q]);
    if (lane == 63) red[wid][q] = w;
  }
#pragma unroll
  for (int c = 0; c < 9; ++c) {
    float w = wave_sum63(sm[c]);
    if (lane == 63) red[wid][45 + c] = w;
  }
  __syncthreads();
  if (tid < 54) {
    float tot = red[0][tid] + red[1][tid] + red[2][tid] + red[3][tid];
    if (tid < 45) {
      int i = 0, rem = tid;
      while (rem >= 9 - i) { rem -= 9 - i; ++i; }
      int j = i + rem;
      atomicAdd(&acc[9 + i * 9 + j], tot);
    } else {
      atomicAdd(&acc[tid - 45], tot);
    }
  }
}

// ---------------- moments for C=64: A^T A GEMM tile over point chunks ----------------
__global__ __launch_bounds__(256) void moments64_kernel(const float* __restrict__ xT,
                                                        float* __restrict__ acc) {
  __shared__ float sm[32 * 68];  // [p][c] padded to 68
  const int tid = threadIdx.x;
  const int ti = (tid & 15) * 4;
  const int tj = (tid >> 4) * 4;
  float av[4][4];
#pragma unroll
  for (int i = 0; i < 4; ++i)
#pragma unroll
    for (int j = 0; j < 4; ++j) av[i][j] = 0.f;
  float s = 0.f;
  for (int ch = 0; ch < 16; ++ch) {
    const int p0 = blockIdx.x * 512 + ch * 32;
#pragma unroll
    for (int k = 0; k < 8; ++k) {
      int e = tid + k * 256;
      int c = e >> 5, pp = e & 31;
      sm[pp * 68 + c] = xT[(size_t)c * N + p0 + pp];
    }
    __syncthreads();
#pragma unroll
    for (int p = 0; p < 32; ++p) {
      float4 a = *reinterpret_cast<const float4*>(&sm[p * 68 + ti]);
      float4 bq = *reinterpret_cast<const float4*>(&sm[p * 68 + tj]);
      av[0][0] = fmaf(a.x, bq.x, av[0][0]); av[0][1] = fmaf(a.x, bq.y, av[0][1]);
      av[0][2] = fmaf(a.x, bq.z, av[0][2]); av[0][3] = fmaf(a.x, bq.w, av[0][3]);
      av[1][0] = fmaf(a.y, bq.x, av[1][0]); av[1][1] = fmaf(a.y, bq.y, av[1][1]);
      av[1][2] = fmaf(a.y, bq.z, av[1][2]); av[1][3] = fmaf(a.y, bq.w, av[1][3]);
      av[2][0] = fmaf(a.z, bq.x, av[2][0]); av[2][1] = fmaf(a.z, bq.y, av[2][1]);
      av[2][2] = fmaf(a.z, bq.z, av[2][2]); av[2][3] = fmaf(a.z, bq.w, av[2][3]);
      av[3][0] = fmaf(a.w, bq.x, av[3][0]); av[3][1] = fmaf(a.w, bq.y, av[3][1]);
      av[3][2] = fmaf(a.w, bq.z, av[3][2]); av[3][3] = fmaf(a.w, bq.w, av[3][3]);
    }
    if (tid < 64) {
#pragma unroll
      for (int p = 0; p < 32; ++p) s += sm[p * 68 + tid];
    }
    __syncthreads();
  }
#pragma unroll
  for (int i = 0; i < 4; ++i)
#pragma unroll
    for (int j = 0; j < 4; ++j) atomicAdd(&acc[64 + (ti + i) * 64 + (tj + j)], av[i][j]);
  if (tid < 64) atomicAdd(&acc[tid], s);
}

// ---------------- stats transform: analytic mean/var -> scale/shift ----------------
__global__ void xform1_kernel(const float* __restrict__ a, const float* __restrict__ W,
                              const float* __restrict__ bb, const float* __restrict__ g,
                              const float* __restrict__ be, float* __restrict__ sc,
                              float* __restrict__ sh) {
  const int d = threadIdx.x;  // 64
  const float invN = 1.0f / (float)N;
  float mu[9];
#pragma unroll
  for (int i = 0; i < 9; ++i) mu[i] = a[i] * invN;
  float m = bb[d];
#pragma unroll
  for (int i = 0; i < 9; ++i) m = fmaf(mu[i], W[i * 64 + d], m);
  float var = 0.f;
#pragma unroll
  for (int i = 0; i < 9; ++i) {
    float wi = W[i * 64 + d];
#pragma unroll
    for (int j = 0; j < 9; ++j) {
      float E = a[9 + (i <= j ? i * 9 + j : j * 9 + i)] * invN;
      float C = fmaf(-mu[i], mu[j], E);
      var = fmaf(wi * W[j * 64 + d], C, var);
    }
  }
  float s = g[d] / sqrtf(var + 1e-5f);
  sc[d] = s;
  sh[d] = fmaf(s, bb[d] - m, be[d]);
}

template <int COUT>
__global__ void xform64_kernel(const float* __restrict__ a, const float* __restrict__ W,
                               const float* __restrict__ bb, const float* __restrict__ g,
                               const float* __restrict__ be, float* __restrict__ sc,
                               float* __restrict__ sh) {
  constexpr int NQ = 256 / COUT;  // 4 (COUT=64) or 2 (COUT=128)
  constexpr int CH = 64 / NQ;
  __shared__ float smu[64];
  __shared__ float pvar[NQ][COUT];
  const int tid = threadIdx.x;
  const int d = tid % COUT;
  const int q = tid / COUT;
  const float invN = 1.0f / (float)N;
  if (tid < 64) smu[tid] = a[tid] * invN;
  __syncthreads();
  float var = 0.f;
  for (int i = q * CH; i < (q + 1) * CH; ++i) {
    float wi = W[i * COUT + d];
    float mi = smu[i];
    for (int j = 0; j < 64; ++j) {
      float C = fmaf(-mi, smu[j], a[64 + i * 64 + j] * invN);
      var = fmaf(wi * W[j * COUT + d], C, var);
    }
  }
  pvar[q][d] = var;
  __syncthreads();
  if (q == 0) {
    for (int k = 1; k < NQ; ++k) var += pvar[k][d];
    float m = bb[d];
    for (int i = 0; i < 64; ++i) m = fmaf(smu[i], W[i * COUT + d], m);
    float s = g[d] / sqrtf(var + 1e-5f);
    sc[d] = s;
    sh[d] = fmaf(s, bb[d] - m, be[d]);
  }
}

// ---------------- fused matmul + normalize + relu (thread-per-point) ----------------
template <int CIN, int COUT>
__global__ __launch_bounds__(256) void mm_kernel(const float* __restrict__ xin,
                                                 const float* __restrict__ W,
                                                 const float* __restrict__ sc,
                                                 const float* __restrict__ sh,
                                                 float* __restrict__ xout) {
  const int p = blockIdx.x * 256 + threadIdx.x;
  float acc[COUT];
#pragma unroll
  for (int co = 0; co < COUT; ++co) acc[co] = 0.f;
  for (int ci = 0; ci < CIN; ++ci) {
    float xv = xin[(size_t)ci * N + p];
#pragma unroll
    for (int co = 0; co < COUT; ++co) acc[co] = fmaf(xv, W[ci * COUT + co], acc[co]);
  }
#pragma unroll
  for (int co = 0; co < COUT; ++co) {
    float v = fmaxf(0.f, fmaf(acc[co], sc[co], sh[co]));
    xout[(size_t)co * N + p] = v;
  }
}

// ---------------- final: matmul + normalize + relu + max over K (DPP) ----------------
#define DPPMAX(ctrl, rmask)                                                               \
  v = fmaxf(v, __int_as_float(__builtin_amdgcn_update_dpp(                                \
                  __float_as_int(v), __float_as_int(v), ctrl, rmask, 0xf, false)));

__global__ __launch_bounds__(256)
__attribute__((amdgpu_waves_per_eu(2, 2)))
void mm_final_kernel(const float* __restrict__ xin,
                     const float* __restrict__ W,
                     const float* __restrict__ sc,
                     const float* __restrict__ sh,
                     float* __restrict__ outp) {
  const int p = blockIdx.x * 256 + threadIdx.x;
  float acc[128];
#pragma unroll
  for (int co = 0; co < 128; ++co) acc[co] = 0.f;
  for (int ci = 0; ci < 64; ++ci) {
    float xv = xin[(size_t)ci * N + p];
#pragma unroll
    for (int co = 0; co < 128; ++co) acc[co] = fmaf(xv, W[ci * 128 + co], acc[co]);
  }
  const int c = p >> 5;
  const bool wlast = (threadIdx.x & 31) == 31;
#pragma unroll
  for (int co = 0; co < 128; ++co) {
    float v = fmaxf(0.f, fmaf(acc[co], sc[co], sh[co]));
    DPPMAX(0xB1, 0xf)   // quad_perm xor1
    DPPMAX(0x4E, 0xf)   // quad_perm xor2
    DPPMAX(0x124, 0xf)  // row_ror:4
    DPPMAX(0x128, 0xf)  // row_ror:8
    DPPMAX(0x142, 0xa)  // row_bcast15 -> lanes 31/63 cover their 32-group
    if (wlast) outp[(size_t)c * 128 + co] = v;
  }
}

extern "C" void kernel_launch(void* const* d_in, const int* in_sizes, int n_in,
                              void* d_out, int out_size, void* d_ws, size_t ws_size,
                              hipStream_t stream) {
  const float* xyz = (const float*)d_in[0];
  const float* pts = (const float*)d_in[1];
  const float* W0 = (const float*)d_in[2];
  const float* b0 = (const float*)d_in[3];
  const float* g0 = (const float*)d_in[4];
  const float* be0 = (const float*)d_in[5];
  const float* W1 = (const float*)d_in[6];
  const float* b1 = (const float*)d_in[7];
  const float* g1 = (const float*)d_in[8];
  const float* be1 = (const float*)d_in[9];
  const float* W2 = (const float*)d_in[10];
  const float* b2 = (const float*)d_in[11];
  const float* g2 = (const float*)d_in[12];
  const float* be2 = (const float*)d_in[13];

  float* out = (float*)d_out;
  float* newxyz = out;                // (B,S,3)
  float* outpts = out + NB * NS * 3;  // (B,S,128)

  float* ws = (float*)d_ws;
  float* x0T = ws;                      // 9N
  float* x1T = ws + (size_t)9 * N;      // 64N
  float* x2T = ws + (size_t)73 * N;     // 64N
  float* scsh = ws + (size_t)137 * N;   // 512 floats
  float* sc1 = scsh, *sh1 = scsh + 64;
  float* sc2 = scsh + 128, *sh2 = scsh + 192;
  float* sc3 = scsh + 256, *sh3 = scsh + 384;
  float* cov0 = x1T;  // 90 floats, consumed by xform1 before mm1 writes x1T
  float* cov1 = x2T;  // 4160 floats, consumed by xform2 before mm2 writes x2T
  float* cov2 = x0T;  // 4160 floats, written after x0T is dead (post-mm1)

  hipMemsetAsync(cov0, 0, 90 * sizeof(float), stream);
  hipMemsetAsync(cov1, 0, 4160 * sizeof(float), stream);

  fps_kernel<<<NB, 512, 0, stream>>>(xyz, newxyz);
  ballq_kernel<<<(NB * NS) / 4, 256, 0, stream>>>(xyz, pts, newxyz, x0T);

  moments9_kernel<<<256, 256, 0, stream>>>(x0T, cov0);
  xform1_kernel<<<1, 64, 0, stream>>>(cov0, W0, b0, g0, be0, sc1, sh1);
  mm_kernel<9, 64><<<N / 256, 256, 0, stream>>>(x0T, W0, sc1, sh1, x1T);

  moments64_kernel<<<512, 256, 0, stream>>>(x1T, cov1);
  xform64_kernel<64><<<1, 256, 0, stream>>>(cov1, W1, b1, g1, be1, sc2, sh2);
  mm_kernel<64, 64><<<N / 256, 256, 0, stream>>>(x1T, W1, sc2, sh2, x2T);

  hipMemsetAsync(cov2, 0, 4160 * sizeof(float), stream);
  moments64_kernel<<<512, 256, 0, stream>>>(x2T, cov2);
  xform64_kernel<128><<<1, 256, 0, stream>>>(cov2, W2, b2, g2, be2, sc3, sh3);
  mm_final_kernel<<<N / 256, 256, 0, stream>>>(x2T, W2, sc3, sh3, outpts);
}

// Round 13
// 1654.088 us; speedup vs baseline: 1.4141x; 1.0667x over previous
//
#include <hip/hip_runtime.h>
#include <cstdint>
#include <cstddef>

#define NB 8
#define NPT 8192
#define NS 1024
#define NK 32
static constexpr int N = NB * NS * NK;  // 262144 grouped points

typedef float v2f __attribute__((ext_vector_type(2)));
typedef unsigned long long u64;

// ---------------- DPP helpers ----------------
// wave64 sum-reduce; valid result in lane 63 only.
__device__ __forceinline__ float wave_sum63(float v) {
  v += __int_as_float(__builtin_amdgcn_update_dpp(0, __float_as_int(v), 0x111, 0xf, 0xf, true));
  v += __int_as_float(__builtin_amdgcn_update_dpp(0, __float_as_int(v), 0x112, 0xf, 0xf, true));
  v += __int_as_float(__builtin_amdgcn_update_dpp(0, __float_as_int(v), 0x114, 0xf, 0xf, true));
  v += __int_as_float(__builtin_amdgcn_update_dpp(0, __float_as_int(v), 0x118, 0xf, 0xf, true));
  v += __int_as_float(__builtin_amdgcn_update_dpp(0, __float_as_int(v), 0x142, 0xa, 0xf, true));
  v += __int_as_float(__builtin_amdgcn_update_dpp(0, __float_as_int(v), 0x143, 0xc, 0xf, true));
  return v;
}

// ---------------- FPS (r8-exact, 883 us proven): packed-u64 DPP argmax ----------------
// pk = (float_bits(bv) << 32) | ~bi : distances >= 0 so float bits are monotone
// as u32; for equal bv, larger ~bi = smaller index (numpy first-max tie-break).
#define FPS_DPP_STEP_PK(ctrl, rmask)                                                      \
  {                                                                                       \
    unsigned lo = (unsigned)pk, hi = (unsigned)(pk >> 32);                                \
    unsigned slo = __builtin_amdgcn_update_dpp(lo, lo, ctrl, rmask, 0xf, false);          \
    unsigned shi = __builtin_amdgcn_update_dpp(hi, hi, ctrl, rmask, 0xf, false);          \
    u64 sp = ((u64)shi << 32) | slo;                                                      \
    pk = sp > pk ? sp : pk;                                                               \
  }

__global__ __launch_bounds__(256)
__attribute__((amdgpu_waves_per_eu(1, 1)))
void fps_kernel(const float* __restrict__ xyz, float* __restrict__ newxyz) {
  const int b = blockIdx.x;
  const int t = threadIdx.x;
  const float* X = xyz + (size_t)b * NPT * 3;
  __shared__ float lx[NPT * 3];   // 96 KB xyz copy (winner-coord fetch by index)
  __shared__ float cent[NS * 3];  // 12 KB centroid buffer, dumped at the end
  __shared__ u64 warr[2][4];      // per-wave packed winner, parity-buffered
#pragma unroll
  for (int i = 0; i < (NPT * 3) / 256; ++i) lx[t + i * 256] = X[t + i * 256];

  v2f px[16], py[16], pz[16], dst[16];
#pragma unroll
  for (int m = 0; m < 16; ++m) {
    int p0 = t + m * 512;
    int p1 = t + m * 512 + 256;
    px[m] = (v2f){X[p0 * 3 + 0], X[p1 * 3 + 0]};
    py[m] = (v2f){X[p0 * 3 + 1], X[p1 * 3 + 1]};
    pz[m] = (v2f){X[p0 * 3 + 2], X[p1 * 3 + 2]};
    dst[m] = (v2f){1e10f, 1e10f};
  }
#pragma unroll
  for (int m = 0; m < 16; ++m) {
    asm volatile("" : "+v"(px[m]), "+v"(py[m]), "+v"(pz[m]));
  }
  float cx = X[0], cy = X[1], cz = X[2];
  __syncthreads();
  for (int s = 0; s < NS; ++s) {
    if (t == 0) {
      cent[s * 3 + 0] = cx; cent[s * 3 + 1] = cy; cent[s * 3 + 2] = cz;
    }
    float bv = -1.0f;
    int bj = 0;
    {
#pragma clang fp contract(off)
      // per-component rounding identical to scalar RN; contract(off) forbids
      // FMA fusing so order matches numpy: ((dx*dx + dy*dy) + dz*dz)
      const v2f cxv = {cx, cx}, cyv = {cy, cy}, czv = {cz, cz};
#pragma unroll
      for (int m = 0; m < 16; ++m) {
        v2f dx = px[m] - cxv;
        v2f dy = py[m] - cyv;
        v2f dz = pz[m] - czv;
        v2f d = (dx * dx + dy * dy) + dz * dz;
        v2f nd = __builtin_elementwise_min(dst[m], d);
        dst[m] = nd;
        // ascending global index order (j=2m then 2m+1); strict > keeps first max
        if (nd.x > bv) { bv = nd.x; bj = 2 * m; }
        if (nd.y > bv) { bv = nd.y; bj = 2 * m + 1; }
      }
    }
    const int bi = t | (bj << 8);  // == t + bj*256 = global point index
    u64 pk = ((u64)(unsigned)__float_as_int(bv) << 32) | (unsigned)~bi;
    FPS_DPP_STEP_PK(0x111, 0xf)  // row_shr:1
    FPS_DPP_STEP_PK(0x112, 0xf)  // row_shr:2
    FPS_DPP_STEP_PK(0x114, 0xf)  // row_shr:4
    FPS_DPP_STEP_PK(0x118, 0xf)  // row_shr:8
    FPS_DPP_STEP_PK(0x142, 0xa)  // row_bcast15
    FPS_DPP_STEP_PK(0x143, 0xc)  // row_bcast31 -> lane63 = wave winner
    const int par = s & 1;
    if ((t & 63) == 63) warr[par][t >> 6] = pk;
    __syncthreads();
    u64 w = warr[par][0];
    {
      u64 w1 = warr[par][1]; w = w1 > w ? w1 : w;
      u64 w2 = warr[par][2]; w = w2 > w ? w2 : w;
      u64 w3 = warr[par][3]; w = w3 > w ? w3 : w;
    }
    const int i0 = (int)(~(unsigned)w) & (NPT - 1);  // winner point index
    cx = lx[i0 * 3 + 0]; cy = lx[i0 * 3 + 1]; cz = lx[i0 * 3 + 2];
  }
  __syncthreads();
  float* ob = newxyz + (size_t)b * NS * 3;
#pragma unroll
  for (int i = 0; i < 12; ++i) ob[t + i * 256] = cent[t + i * 256];
}

// ---------------- Ball query + gather + concat -> x0^T (channel-major) ----------------
__global__ __launch_bounds__(256) void ballq_kernel(const float* __restrict__ xyz,
                                                    const float* __restrict__ pts,
                                                    const float* __restrict__ newxyz,
                                                    float* __restrict__ x0T) {
  const int wid = threadIdx.x >> 6;
  const int lane = threadIdx.x & 63;
  const int gw = blockIdx.x * 4 + wid;  // global center 0..8191
  const int b = gw >> 10;
  const float* X = xyz + (size_t)b * NPT * 3;
  const float cx = newxyz[gw * 3 + 0], cy = newxyz[gw * 3 + 1], cz = newxyz[gw * 3 + 2];
  const float r2 = (float)(0.2 * 0.2);
  const float s2c = __fadd_rn(__fadd_rn(__fmul_rn(cx, cx), __fmul_rn(cy, cy)), __fmul_rn(cz, cz));
  __shared__ int sel[4][NK];
  int cnt = 0;
  for (int chunk = 0; chunk < NPT / 64; ++chunk) {
    int p = chunk * 64 + lane;
    float x = X[p * 3 + 0], y = X[p * 3 + 1], z = X[p * 3 + 2];
    float s2p = __fadd_rn(__fadd_rn(__fmul_rn(x, x), __fmul_rn(y, y)), __fmul_rn(z, z));
    float dot = __fadd_rn(__fadd_rn(__fmul_rn(cx, x), __fmul_rn(cy, y)), __fmul_rn(cz, z));
    float sq = __fsub_rn(__fadd_rn(s2c, s2p), __fmul_rn(2.0f, dot));
    bool in = !(sq > r2);
    unsigned long long m = __ballot(in);
    if (in) {
      int slot = cnt + (int)__popcll(m & ((1ull << lane) - 1ull));
      if (slot < NK) sel[wid][slot] = p;
    }
    cnt += (int)__popcll(m);
    if (cnt >= NK) break;  // wave-uniform
  }
  __threadfence_block();
  int first = sel[wid][0];  // center itself always in-radius (sq == 0 exactly)
  if (cnt < NK) {
    for (int s = cnt + lane; s < NK; s += 64) sel[wid][s] = first;
  }
  __threadfence_block();
  if (lane < NK) {
    int p = sel[wid][lane];
    const float* f = pts + ((size_t)b * NPT + p) * 6;
    const size_t col = (size_t)gw * NK + lane;
    x0T[0 * (size_t)N + col] = f[0];
    x0T[1 * (size_t)N + col] = f[1];
    x0T[2 * (size_t)N + col] = f[2];
    x0T[3 * (size_t)N + col] = f[3];
    x0T[4 * (size_t)N + col] = f[4];
    x0T[5 * (size_t)N + col] = f[5];
    x0T[6 * (size_t)N + col] = X[p * 3 + 0] - cx;
    x0T[7 * (size_t)N + col] = X[p * 3 + 1] - cy;
    x0T[8 * (size_t)N + col] = X[p * 3 + 2] - cz;
  }
}

// ---------------- moments for C=9: per-thread upper-tri outer product ----------------
__device__ __forceinline__ constexpr int tri9(int i, int j) { return 9 * i - i * (i + 1) / 2 + j; }

__global__ __launch_bounds__(256) void moments9_kernel(const float* __restrict__ xT,
                                                       float* __restrict__ acc) {
  const int tid = threadIdx.x;
  const int lane = tid & 63, wid = tid >> 6;
  float a45[45];
  float sm[9];
#pragma unroll
  for (int q = 0; q < 45; ++q) a45[q] = 0.f;
#pragma unroll
  for (int c = 0; c < 9; ++c) sm[c] = 0.f;
  const int p0 = blockIdx.x * 1024 + tid;
  for (int k = 0; k < 4; ++k) {
    int p = p0 + k * 256;
    float v[9];
#pragma unroll
    for (int c = 0; c < 9; ++c) v[c] = xT[(size_t)c * N + p];
#pragma unroll
    for (int c = 0; c < 9; ++c) sm[c] += v[c];
#pragma unroll
    for (int i = 0; i < 9; ++i)
#pragma unroll
      for (int j = i; j < 9; ++j) a45[tri9(i, j)] = fmaf(v[i], v[j], a45[tri9(i, j)]);
  }
  __shared__ float red[4][54];
#pragma unroll
  for (int q = 0; q < 45; ++q) {
    float w = wave_sum63(a45[q]);
    if (lane == 63) red[wid][q] = w;
  }
#pragma unroll
  for (int c = 0; c < 9; ++c) {
    float w = wave_sum63(sm[c]);
    if (lane == 63) red[wid][45 + c] = w;
  }
  __syncthreads();
  if (tid < 54) {
    float tot = red[0][tid] + red[1][tid] + red[2][tid] + red[3][tid];
    if (tid < 45) {
      int i = 0, rem = tid;
      while (rem >= 9 - i) { rem -= 9 - i; ++i; }
      int j = i + rem;
      atomicAdd(&acc[9 + i * 9 + j], tot);
    } else {
      atomicAdd(&acc[tid - 45], tot);
    }
  }
}

// ---------------- moments for C=64: A^T A GEMM tile over point chunks ----------------
__global__ __launch_bounds__(256) void moments64_kernel(const float* __restrict__ xT,
                                                        float* __restrict__ acc) {
  __shared__ float sm[32 * 68];  // [p][c] padded to 68
  const int tid = threadIdx.x;
  const int ti = (tid & 15) * 4;
  const int tj = (tid >> 4) * 4;
  float av[4][4];
#pragma unroll
  for (int i = 0; i < 4; ++i)
#pragma unroll
    for (int j = 0; j < 4; ++j) av[i][j] = 0.f;
  float s = 0.f;
  for (int ch = 0; ch < 16; ++ch) {
    const int p0 = blockIdx.x * 512 + ch * 32;
#pragma unroll
    for (int k = 0; k < 8; ++k) {
      int e = tid + k * 256;
      int c = e >> 5, pp = e & 31;
      sm[pp * 68 + c] = xT[(size_t)c * N + p0 + pp];
    }
    __syncthreads();
#pragma unroll
    for (int p = 0; p < 32; ++p) {
      float4 a = *reinterpret_cast<const float4*>(&sm[p * 68 + ti]);
      float4 bq = *reinterpret_cast<const float4*>(&sm[p * 68 + tj]);
      av[0][0] = fmaf(a.x, bq.x, av[0][0]); av[0][1] = fmaf(a.x, bq.y, av[0][1]);
      av[0][2] = fmaf(a.x, bq.z, av[0][2]); av[0][3] = fmaf(a.x, bq.w, av[0][3]);
      av[1][0] = fmaf(a.y, bq.x, av[1][0]); av[1][1] = fmaf(a.y, bq.y, av[1][1]);
      av[1][2] = fmaf(a.y, bq.z, av[1][2]); av[1][3] = fmaf(a.y, bq.w, av[1][3]);
      av[2][0] = fmaf(a.z, bq.x, av[2][0]); av[2][1] = fmaf(a.z, bq.y, av[2][1]);
      av[2][2] = fmaf(a.z, bq.z, av[2][2]); av[2][3] = fmaf(a.z, bq.w, av[2][3]);
      av[3][0] = fmaf(a.w, bq.x, av[3][0]); av[3][1] = fmaf(a.w, bq.y, av[3][1]);
      av[3][2] = fmaf(a.w, bq.z, av[3][2]); av[3][3] = fmaf(a.w, bq.w, av[3][3]);
    }
    if (tid < 64) {
#pragma unroll
      for (int p = 0; p < 32; ++p) s += sm[p * 68 + tid];
    }
    __syncthreads();
  }
#pragma unroll
  for (int i = 0; i < 4; ++i)
#pragma unroll
    for (int j = 0; j < 4; ++j) atomicAdd(&acc[64 + (ti + i) * 64 + (tj + j)], av[i][j]);
  if (tid < 64) atomicAdd(&acc[tid], s);
}

// ---------------- stats transform: analytic mean/var -> scale/shift ----------------
__global__ void xform1_kernel(const float* __restrict__ a, const float* __restrict__ W,
                              const float* __restrict__ bb, const float* __restrict__ g,
                              const float* __restrict__ be, float* __restrict__ sc,
                              float* __restrict__ sh) {
  const int d = threadIdx.x;  // 64
  const float invN = 1.0f / (float)N;
  float mu[9];
#pragma unroll
  for (int i = 0; i < 9; ++i) mu[i] = a[i] * invN;
  float m = bb[d];
#pragma unroll
  for (int i = 0; i < 9; ++i) m = fmaf(mu[i], W[i * 64 + d], m);
  float var = 0.f;
#pragma unroll
  for (int i = 0; i < 9; ++i) {
    float wi = W[i * 64 + d];
#pragma unroll
    for (int j = 0; j < 9; ++j) {
      float E = a[9 + (i <= j ? i * 9 + j : j * 9 + i)] * invN;
      float C = fmaf(-mu[i], mu[j], E);
      var = fmaf(wi * W[j * 64 + d], C, var);
    }
  }
  float s = g[d] / sqrtf(var + 1e-5f);
  sc[d] = s;
  sh[d] = fmaf(s, bb[d] - m, be[d]);
}

template <int COUT>
__global__ void xform64_kernel(const float* __restrict__ a, const float* __restrict__ W,
                               const float* __restrict__ bb, const float* __restrict__ g,
                               const float* __restrict__ be, float* __restrict__ sc,
                               float* __restrict__ sh) {
  constexpr int NQ = 256 / COUT;  // 4 (COUT=64) or 2 (COUT=128)
  constexpr int CH = 64 / NQ;
  __shared__ float smu[64];
  __shared__ float pvar[NQ][COUT];
  const int tid = threadIdx.x;
  const int d = tid % COUT;
  const int q = tid / COUT;
  const float invN = 1.0f / (float)N;
  if (tid < 64) smu[tid] = a[tid] * invN;
  __syncthreads();
  float var = 0.f;
  for (int i = q * CH; i < (q + 1) * CH; ++i) {
    float wi = W[i * COUT + d];
    float mi = smu[i];
    for (int j = 0; j < 64; ++j) {
      float C = fmaf(-mi, smu[j], a[64 + i * 64 + j] * invN);
      var = fmaf(wi * W[j * COUT + d], C, var);
    }
  }
  pvar[q][d] = var;
  __syncthreads();
  if (q == 0) {
    for (int k = 1; k < NQ; ++k) var += pvar[k][d];
    float m = bb[d];
    for (int i = 0; i < 64; ++i) m = fmaf(smu[i], W[i * COUT + d], m);
    float s = g[d] / sqrtf(var + 1e-5f);
    sc[d] = s;
    sh[d] = fmaf(s, bb[d] - m, be[d]);
  }
}

// ---------------- fused matmul + normalize + relu, CO-chunked (no spill) -------------
// acc[32] (~45 VGPR) fits the default 8-waves/EU budget: full occupancy AND no
// scratch. Grid = (N/256) * (COUT/32); consecutive blocks share the same point
// range (chunk index fastest) so xin re-reads hit L2.
template <int CIN, int COUT>
__global__ __launch_bounds__(256) void mm_kernel(const float* __restrict__ xin,
                                                 const float* __restrict__ W,
                                                 const float* __restrict__ sc,
                                                 const float* __restrict__ sh,
                                                 float* __restrict__ xout) {
  constexpr int NCH = COUT / 32;
  const int pb = blockIdx.x / NCH;
  const int co0 = (blockIdx.x % NCH) * 32;
  const int p = pb * 256 + threadIdx.x;
  float acc[32];
#pragma unroll
  for (int i = 0; i < 32; ++i) acc[i] = 0.f;
  for (int ci = 0; ci < CIN; ++ci) {
    float xv = xin[(size_t)ci * N + p];
#pragma unroll
    for (int i = 0; i < 32; ++i) acc[i] = fmaf(xv, W[ci * COUT + co0 + i], acc[i]);
  }
#pragma unroll
  for (int i = 0; i < 32; ++i) {
    float v = fmaxf(0.f, fmaf(acc[i], sc[co0 + i], sh[co0 + i]));
    xout[(size_t)(co0 + i) * N + p] = v;
  }
}

// ---------------- final: matmul + normalize + relu + max over K, CO-chunked ----------
#define DPPMAX(ctrl, rmask)                                                               \
  v = fmaxf(v, __int_as_float(__builtin_amdgcn_update_dpp(                                \
                  __float_as_int(v), __float_as_int(v), ctrl, rmask, 0xf, false)));

__global__ __launch_bounds__(256) void mm_final_kernel(const float* __restrict__ xin,
                                                       const float* __restrict__ W,
                                                       const float* __restrict__ sc,
                                                       const float* __restrict__ sh,
                                                       float* __restrict__ outp) {
  constexpr int NCH = 4;  // 128 / 32
  const int pb = blockIdx.x / NCH;
  const int co0 = (blockIdx.x % NCH) * 32;
  const int p = pb * 256 + threadIdx.x;
  float acc[32];
#pragma unroll
  for (int i = 0; i < 32; ++i) acc[i] = 0.f;
  for (int ci = 0; ci < 64; ++ci) {
    float xv = xin[(size_t)ci * N + p];
#pragma unroll
    for (int i = 0; i < 32; ++i) acc[i] = fmaf(xv, W[ci * 128 + co0 + i], acc[i]);
  }
  const int c = p >> 5;
  const bool wlast = (threadIdx.x & 31) == 31;
#pragma unroll
  for (int i = 0; i < 32; ++i) {
    float v = fmaxf(0.f, fmaf(acc[i], sc[co0 + i], sh[co0 + i]));
    DPPMAX(0xB1, 0xf)   // quad_perm xor1
    DPPMAX(0x4E, 0xf)   // quad_perm xor2
    DPPMAX(0x124, 0xf)  // row_ror:4
    DPPMAX(0x128, 0xf)  // row_ror:8
    DPPMAX(0x142, 0xa)  // row_bcast15 -> lanes 31/63 cover their 32-group
    if (wlast) outp[(size_t)c * 128 + co0 + i] = v;
  }
}

extern "C" void kernel_launch(void* const* d_in, const int* in_sizes, int n_in,
                              void* d_out, int out_size, void* d_ws, size_t ws_size,
                              hipStream_t stream) {
  const float* xyz = (const float*)d_in[0];
  const float* pts = (const float*)d_in[1];
  const float* W0 = (const float*)d_in[2];
  const float* b0 = (const float*)d_in[3];
  const float* g0 = (const float*)d_in[4];
  const float* be0 = (const float*)d_in[5];
  const float* W1 = (const float*)d_in[6];
  const float* b1 = (const float*)d_in[7];
  const float* g1 = (const float*)d_in[8];
  const float* be1 = (const float*)d_in[9];
  const float* W2 = (const float*)d_in[10];
  const float* b2 = (const float*)d_in[11];
  const float* g2 = (const float*)d_in[12];
  const float* be2 = (const float*)d_in[13];

  float* out = (float*)d_out;
  float* newxyz = out;                // (B,S,3)
  float* outpts = out + NB * NS * 3;  // (B,S,128)

  float* ws = (float*)d_ws;
  float* x0T = ws;                      // 9N
  float* x1T = ws + (size_t)9 * N;      // 64N
  float* x2T = ws + (size_t)73 * N;     // 64N
  float* scsh = ws + (size_t)137 * N;   // 512 floats
  float* sc1 = scsh, *sh1 = scsh + 64;
  float* sc2 = scsh + 128, *sh2 = scsh + 192;
  float* sc3 = scsh + 256, *sh3 = scsh + 384;
  float* cov0 = x1T;  // 90 floats, consumed by xform1 before mm1 writes x1T
  float* cov1 = x2T;  // 4160 floats, consumed by xform2 before mm2 writes x2T
  float* cov2 = x0T;  // 4160 floats, written after x0T is dead (post-mm1)

  hipMemsetAsync(cov0, 0, 90 * sizeof(float), stream);
  hipMemsetAsync(cov1, 0, 4160 * sizeof(float), stream);

  fps_kernel<<<NB, 256, 0, stream>>>(xyz, newxyz);
  ballq_kernel<<<(NB * NS) / 4, 256, 0, stream>>>(xyz, pts, newxyz, x0T);

  moments9_kernel<<<256, 256, 0, stream>>>(x0T, cov0);
  xform1_kernel<<<1, 64, 0, stream>>>(cov0, W0, b0, g0, be0, sc1, sh1);
  mm_kernel<9, 64><<<(N / 256) * 2, 256, 0, stream>>>(x0T, W0, sc1, sh1, x1T);

  moments64_kernel<<<512, 256, 0, stream>>>(x1T, cov1);
  xform64_kernel<64><<<1, 256, 0, stream>>>(cov1, W1, b1, g1, be1, sc2, sh2);
  mm_kernel<64, 64><<<(N / 256) * 2, 256, 0, stream>>>(x1T, W1, sc2, sh2, x2T);

  hipMemsetAsync(cov2, 0, 4160 * sizeof(float), stream);
  moments64_kernel<<<512, 256, 0, stream>>>(x2T, cov2);
  xform64_kernel<128><<<1, 256, 0, stream>>>(cov2, W2, b2, g2, be2, sc3, sh3);
  mm_final_kernel<<<(N / 256) * 4, 256, 0, stream>>>(x2T, W2, sc3, sh3, outpts);
}

// Round 14
// 1458.099 us; speedup vs baseline: 1.6042x; 1.1344x over previous
//
#include <hip/hip_runtime.h>
#include <cstdint>
#include <cstddef>

#define NB 8
#define NPT 8192
#define NS 1024
#define NK 32
static constexpr int N = NB * NS * NK;  // 262144 grouped points

typedef float v2f __attribute__((ext_vector_type(2)));
typedef unsigned long long u64;

// ---------------- DPP helpers ----------------
// wave64 sum-reduce; valid result in lane 63 only.
__device__ __forceinline__ float wave_sum63(float v) {
  v += __int_as_float(__builtin_amdgcn_update_dpp(0, __float_as_int(v), 0x111, 0xf, 0xf, true));
  v += __int_as_float(__builtin_amdgcn_update_dpp(0, __float_as_int(v), 0x112, 0xf, 0xf, true));
  v += __int_as_float(__builtin_amdgcn_update_dpp(0, __float_as_int(v), 0x114, 0xf, 0xf, true));
  v += __int_as_float(__builtin_amdgcn_update_dpp(0, __float_as_int(v), 0x118, 0xf, 0xf, true));
  v += __int_as_float(__builtin_amdgcn_update_dpp(0, __float_as_int(v), 0x142, 0xa, 0xf, true));
  v += __int_as_float(__builtin_amdgcn_update_dpp(0, __float_as_int(v), 0x143, 0xc, 0xf, true));
  return v;
}

// ---------------- FPS (r8-exact, ~880 us proven): packed-u64 DPP argmax ---------------
// pk = (float_bits(bv) << 32) | ~bi : distances >= 0 so float bits are monotone
// as u32; for equal bv, larger ~bi = smaller index (numpy first-max tie-break).
#define FPS_DPP_STEP_PK(ctrl, rmask)                                                      \
  {                                                                                       \
    unsigned lo = (unsigned)pk, hi = (unsigned)(pk >> 32);                                \
    unsigned slo = __builtin_amdgcn_update_dpp(lo, lo, ctrl, rmask, 0xf, false);          \
    unsigned shi = __builtin_amdgcn_update_dpp(hi, hi, ctrl, rmask, 0xf, false);          \
    u64 sp = ((u64)shi << 32) | slo;                                                      \
    pk = sp > pk ? sp : pk;                                                               \
  }

__global__ __launch_bounds__(256)
__attribute__((amdgpu_waves_per_eu(1, 1)))
void fps_kernel(const float* __restrict__ xyz, float* __restrict__ newxyz) {
  const int b = blockIdx.x;
  const int t = threadIdx.x;
  const float* X = xyz + (size_t)b * NPT * 3;
  __shared__ float lx[NPT * 3];   // 96 KB xyz copy (winner-coord fetch by index)
  __shared__ float cent[NS * 3];  // 12 KB centroid buffer, dumped at the end
  __shared__ u64 warr[2][4];      // per-wave packed winner, parity-buffered
#pragma unroll
  for (int i = 0; i < (NPT * 3) / 256; ++i) lx[t + i * 256] = X[t + i * 256];

  v2f px[16], py[16], pz[16], dst[16];
#pragma unroll
  for (int m = 0; m < 16; ++m) {
    int p0 = t + m * 512;
    int p1 = t + m * 512 + 256;
    px[m] = (v2f){X[p0 * 3 + 0], X[p1 * 3 + 0]};
    py[m] = (v2f){X[p0 * 3 + 1], X[p1 * 3 + 1]};
    pz[m] = (v2f){X[p0 * 3 + 2], X[p1 * 3 + 2]};
    dst[m] = (v2f){1e10f, 1e10f};
  }
#pragma unroll
  for (int m = 0; m < 16; ++m) {
    asm volatile("" : "+v"(px[m]), "+v"(py[m]), "+v"(pz[m]));
  }
  float cx = X[0], cy = X[1], cz = X[2];
  __syncthreads();
  for (int s = 0; s < NS; ++s) {
    if (t == 0) {
      cent[s * 3 + 0] = cx; cent[s * 3 + 1] = cy; cent[s * 3 + 2] = cz;
    }
    float bv = -1.0f;
    int bj = 0;
    {
#pragma clang fp contract(off)
      // per-component rounding identical to scalar RN; contract(off) forbids
      // FMA fusing so order matches numpy: ((dx*dx + dy*dy) + dz*dz)
      const v2f cxv = {cx, cx}, cyv = {cy, cy}, czv = {cz, cz};
#pragma unroll
      for (int m = 0; m < 16; ++m) {
        v2f dx = px[m] - cxv;
        v2f dy = py[m] - cyv;
        v2f dz = pz[m] - czv;
        v2f d = (dx * dx + dy * dy) + dz * dz;
        v2f nd = __builtin_elementwise_min(dst[m], d);
        dst[m] = nd;
        // ascending global index order (j=2m then 2m+1); strict > keeps first max
        if (nd.x > bv) { bv = nd.x; bj = 2 * m; }
        if (nd.y > bv) { bv = nd.y; bj = 2 * m + 1; }
      }
    }
    const int bi = t | (bj << 8);  // == t + bj*256 = global point index
    u64 pk = ((u64)(unsigned)__float_as_int(bv) << 32) | (unsigned)~bi;
    FPS_DPP_STEP_PK(0x111, 0xf)  // row_shr:1
    FPS_DPP_STEP_PK(0x112, 0xf)  // row_shr:2
    FPS_DPP_STEP_PK(0x114, 0xf)  // row_shr:4
    FPS_DPP_STEP_PK(0x118, 0xf)  // row_shr:8
    FPS_DPP_STEP_PK(0x142, 0xa)  // row_bcast15
    FPS_DPP_STEP_PK(0x143, 0xc)  // row_bcast31 -> lane63 = wave winner
    const int par = s & 1;
    if ((t & 63) == 63) warr[par][t >> 6] = pk;
    __syncthreads();
    u64 w = warr[par][0];
    {
      u64 w1 = warr[par][1]; w = w1 > w ? w1 : w;
      u64 w2 = warr[par][2]; w = w2 > w ? w2 : w;
      u64 w3 = warr[par][3]; w = w3 > w ? w3 : w;
    }
    const int i0 = (int)(~(unsigned)w) & (NPT - 1);  // winner point index
    cx = lx[i0 * 3 + 0]; cy = lx[i0 * 3 + 1]; cz = lx[i0 * 3 + 2];
  }
  __syncthreads();
  float* ob = newxyz + (size_t)b * NS * 3;
#pragma unroll
  for (int i = 0; i < 12; ++i) ob[t + i * 256] = cent[t + i * 256];
}

// ---------------- Ball query + gather + concat -> x0^T (channel-major) ----------------
__global__ __launch_bounds__(256) void ballq_kernel(const float* __restrict__ xyz,
                                                    const float* __restrict__ pts,
                                                    const float* __restrict__ newxyz,
                                                    float* __restrict__ x0T) {
  const int wid = threadIdx.x >> 6;
  const int lane = threadIdx.x & 63;
  const int gw = blockIdx.x * 4 + wid;  // global center 0..8191
  const int b = gw >> 10;
  const float* X = xyz + (size_t)b * NPT * 3;
  const float cx = newxyz[gw * 3 + 0], cy = newxyz[gw * 3 + 1], cz = newxyz[gw * 3 + 2];
  const float r2 = (float)(0.2 * 0.2);
  const float s2c = __fadd_rn(__fadd_rn(__fmul_rn(cx, cx), __fmul_rn(cy, cy)), __fmul_rn(cz, cz));
  __shared__ int sel[4][NK];
  int cnt = 0;
  for (int chunk = 0; chunk < NPT / 64; ++chunk) {
    int p = chunk * 64 + lane;
    float x = X[p * 3 + 0], y = X[p * 3 + 1], z = X[p * 3 + 2];
    float s2p = __fadd_rn(__fadd_rn(__fmul_rn(x, x), __fmul_rn(y, y)), __fmul_rn(z, z));
    float dot = __fadd_rn(__fadd_rn(__fmul_rn(cx, x), __fmul_rn(cy, y)), __fmul_rn(cz, z));
    float sq = __fsub_rn(__fadd_rn(s2c, s2p), __fmul_rn(2.0f, dot));
    bool in = !(sq > r2);
    unsigned long long m = __ballot(in);
    if (in) {
      int slot = cnt + (int)__popcll(m & ((1ull << lane) - 1ull));
      if (slot < NK) sel[wid][slot] = p;
    }
    cnt += (int)__popcll(m);
    if (cnt >= NK) break;  // wave-uniform
  }
  __threadfence_block();
  int first = sel[wid][0];  // center itself always in-radius (sq == 0 exactly)
  if (cnt < NK) {
    for (int s = cnt + lane; s < NK; s += 64) sel[wid][s] = first;
  }
  __threadfence_block();
  if (lane < NK) {
    int p = sel[wid][lane];
    const float* f = pts + ((size_t)b * NPT + p) * 6;
    const size_t col = (size_t)gw * NK + lane;
    x0T[0 * (size_t)N + col] = f[0];
    x0T[1 * (size_t)N + col] = f[1];
    x0T[2 * (size_t)N + col] = f[2];
    x0T[3 * (size_t)N + col] = f[3];
    x0T[4 * (size_t)N + col] = f[4];
    x0T[5 * (size_t)N + col] = f[5];
    x0T[6 * (size_t)N + col] = X[p * 3 + 0] - cx;
    x0T[7 * (size_t)N + col] = X[p * 3 + 1] - cy;
    x0T[8 * (size_t)N + col] = X[p * 3 + 2] - cz;
  }
}

// ---------------- moments for C=9: per-thread upper-tri outer product ----------------
__device__ __forceinline__ constexpr int tri9(int i, int j) { return 9 * i - i * (i + 1) / 2 + j; }

__global__ __launch_bounds__(256) void moments9_kernel(const float* __restrict__ xT,
                                                       float* __restrict__ acc) {
  const int tid = threadIdx.x;
  const int lane = tid & 63, wid = tid >> 6;
  float a45[45];
  float sm[9];
#pragma unroll
  for (int q = 0; q < 45; ++q) a45[q] = 0.f;
#pragma unroll
  for (int c = 0; c < 9; ++c) sm[c] = 0.f;
  const int p0 = blockIdx.x * 1024 + tid;
  for (int k = 0; k < 4; ++k) {
    int p = p0 + k * 256;
    float v[9];
#pragma unroll
    for (int c = 0; c < 9; ++c) v[c] = xT[(size_t)c * N + p];
#pragma unroll
    for (int c = 0; c < 9; ++c) sm[c] += v[c];
#pragma unroll
    for (int i = 0; i < 9; ++i)
#pragma unroll
      for (int j = i; j < 9; ++j) a45[tri9(i, j)] = fmaf(v[i], v[j], a45[tri9(i, j)]);
  }
  __shared__ float red[4][54];
#pragma unroll
  for (int q = 0; q < 45; ++q) {
    float w = wave_sum63(a45[q]);
    if (lane == 63) red[wid][q] = w;
  }
#pragma unroll
  for (int c = 0; c < 9; ++c) {
    float w = wave_sum63(sm[c]);
    if (lane == 63) red[wid][45 + c] = w;
  }
  __syncthreads();
  if (tid < 54) {
    float tot = red[0][tid] + red[1][tid] + red[2][tid] + red[3][tid];
    if (tid < 45) {
      int i = 0, rem = tid;
      while (rem >= 9 - i) { rem -= 9 - i; ++i; }
      int j = i + rem;
      atomicAdd(&acc[9 + i * 9 + j], tot);
    } else {
      atomicAdd(&acc[tid - 45], tot);
    }
  }
}

// ---------------- moments for C=64: A^T A GEMM tile over point chunks ----------------
__global__ __launch_bounds__(256) void moments64_kernel(const float* __restrict__ xT,
                                                        float* __restrict__ acc) {
  __shared__ float sm[32 * 68];  // [p][c] padded to 68
  const int tid = threadIdx.x;
  const int ti = (tid & 15) * 4;
  const int tj = (tid >> 4) * 4;
  float av[4][4];
#pragma unroll
  for (int i = 0; i < 4; ++i)
#pragma unroll
    for (int j = 0; j < 4; ++j) av[i][j] = 0.f;
  float s = 0.f;
  for (int ch = 0; ch < 16; ++ch) {
    const int p0 = blockIdx.x * 512 + ch * 32;
#pragma unroll
    for (int k = 0; k < 8; ++k) {
      int e = tid + k * 256;
      int c = e >> 5, pp = e & 31;
      sm[pp * 68 + c] = xT[(size_t)c * N + p0 + pp];
    }
    __syncthreads();
#pragma unroll
    for (int p = 0; p < 32; ++p) {
      float4 a = *reinterpret_cast<const float4*>(&sm[p * 68 + ti]);
      float4 bq = *reinterpret_cast<const float4*>(&sm[p * 68 + tj]);
      av[0][0] = fmaf(a.x, bq.x, av[0][0]); av[0][1] = fmaf(a.x, bq.y, av[0][1]);
      av[0][2] = fmaf(a.x, bq.z, av[0][2]); av[0][3] = fmaf(a.x, bq.w, av[0][3]);
      av[1][0] = fmaf(a.y, bq.x, av[1][0]); av[1][1] = fmaf(a.y, bq.y, av[1][1]);
      av[1][2] = fmaf(a.y, bq.z, av[1][2]); av[1][3] = fmaf(a.y, bq.w, av[1][3]);
      av[2][0] = fmaf(a.z, bq.x, av[2][0]); av[2][1] = fmaf(a.z, bq.y, av[2][1]);
      av[2][2] = fmaf(a.z, bq.z, av[2][2]); av[2][3] = fmaf(a.z, bq.w, av[2][3]);
      av[3][0] = fmaf(a.w, bq.x, av[3][0]); av[3][1] = fmaf(a.w, bq.y, av[3][1]);
      av[3][2] = fmaf(a.w, bq.z, av[3][2]); av[3][3] = fmaf(a.w, bq.w, av[3][3]);
    }
    if (tid < 64) {
#pragma unroll
      for (int p = 0; p < 32; ++p) s += sm[p * 68 + tid];
    }
    __syncthreads();
  }
#pragma unroll
  for (int i = 0; i < 4; ++i)
#pragma unroll
    for (int j = 0; j < 4; ++j) atomicAdd(&acc[64 + (ti + i) * 64 + (tj + j)], av[i][j]);
  if (tid < 64) atomicAdd(&acc[tid], s);
}

// ---------------- stats transform: analytic mean/var -> scale/shift ----------------
__global__ void xform1_kernel(const float* __restrict__ a, const float* __restrict__ W,
                              const float* __restrict__ bb, const float* __restrict__ g,
                              const float* __restrict__ be, float* __restrict__ sc,
                              float* __restrict__ sh) {
  const int d = threadIdx.x;  // 64
  const float invN = 1.0f / (float)N;
  float mu[9];
#pragma unroll
  for (int i = 0; i < 9; ++i) mu[i] = a[i] * invN;
  float m = bb[d];
#pragma unroll
  for (int i = 0; i < 9; ++i) m = fmaf(mu[i], W[i * 64 + d], m);
  float var = 0.f;
#pragma unroll
  for (int i = 0; i < 9; ++i) {
    float wi = W[i * 64 + d];
#pragma unroll
    for (int j = 0; j < 9; ++j) {
      float E = a[9 + (i <= j ? i * 9 + j : j * 9 + i)] * invN;
      float C = fmaf(-mu[i], mu[j], E);
      var = fmaf(wi * W[j * 64 + d], C, var);
    }
  }
  float s = g[d] / sqrtf(var + 1e-5f);
  sc[d] = s;
  sh[d] = fmaf(s, bb[d] - m, be[d]);
}

// ---------------- parallel stats transform: one block PER OUTPUT CHANNEL -------------
// Replaces the single-block xform64 (1 CU, ~2K dependent L2 loads -> latency-
// bound, theorized 150-350 us). 64/128 blocks, cov contraction strip-mined
// over 256 threads with coalesced reads; W column + mu staged in LDS.
template <int COUT>
__global__ __launch_bounds__(256) void xform_par_kernel(const float* __restrict__ a,
                                                        const float* __restrict__ W,
                                                        const float* __restrict__ bb,
                                                        const float* __restrict__ g,
                                                        const float* __restrict__ be,
                                                        float* __restrict__ sc,
                                                        float* __restrict__ sh) {
  const int d = blockIdx.x;
  const int tid = threadIdx.x;
  __shared__ float wl[64];   // W[:,d]
  __shared__ float smu[64];  // mu
  __shared__ float red[4];
  const float invN = 1.0f / (float)N;
  if (tid < 64) {
    wl[tid] = W[tid * COUT + d];
    smu[tid] = a[tid] * invN;
  }
  __syncthreads();
  float part = 0.f;
#pragma unroll
  for (int k = 0; k < 16; ++k) {
    int e = tid + k * 256;           // e = i*64 + j, coalesced over a[]
    int i = e >> 6, j = e & 63;
    float C = fmaf(-smu[i], smu[j], a[64 + e] * invN);
    part = fmaf(wl[i] * wl[j], C, part);
  }
  float wsum = wave_sum63(part);
  if ((tid & 63) == 63) red[tid >> 6] = wsum;
  __syncthreads();
  if (tid == 0) {
    float var = red[0] + red[1] + red[2] + red[3];
    float m = bb[d];
#pragma unroll
    for (int i = 0; i < 64; ++i) m = fmaf(smu[i], wl[i], m);
    float s = g[d] / sqrtf(var + 1e-5f);
    sc[d] = s;
    sh[d] = fmaf(s, bb[d] - m, be[d]);
  }
}

// ---------------- fused matmul + normalize + relu, CO-chunked (no spill) -------------
template <int CIN, int COUT>
__global__ __launch_bounds__(256) void mm_kernel(const float* __restrict__ xin,
                                                 const float* __restrict__ W,
                                                 const float* __restrict__ sc,
                                                 const float* __restrict__ sh,
                                                 float* __restrict__ xout) {
  constexpr int NCH = COUT / 32;
  const int pb = blockIdx.x / NCH;
  const int co0 = (blockIdx.x % NCH) * 32;
  const int p = pb * 256 + threadIdx.x;
  float acc[32];
#pragma unroll
  for (int i = 0; i < 32; ++i) acc[i] = 0.f;
  for (int ci = 0; ci < CIN; ++ci) {
    float xv = xin[(size_t)ci * N + p];
#pragma unroll
    for (int i = 0; i < 32; ++i) acc[i] = fmaf(xv, W[ci * COUT + co0 + i], acc[i]);
  }
#pragma unroll
  for (int i = 0; i < 32; ++i) {
    float v = fmaxf(0.f, fmaf(acc[i], sc[co0 + i], sh[co0 + i]));
    xout[(size_t)(co0 + i) * N + p] = v;
  }
}

// ---------------- final: matmul + normalize + relu + max over K, CO-chunked ----------
#define DPPMAX(ctrl, rmask)                                                               \
  v = fmaxf(v, __int_as_float(__builtin_amdgcn_update_dpp(                                \
                  __float_as_int(v), __float_as_int(v), ctrl, rmask, 0xf, false)));

__global__ __launch_bounds__(256) void mm_final_kernel(const float* __restrict__ xin,
                                                       const float* __restrict__ W,
                                                       const float* __restrict__ sc,
                                                       const float* __restrict__ sh,
                                                       float* __restrict__ outp) {
  constexpr int NCH = 4;  // 128 / 32
  const int pb = blockIdx.x / NCH;
  const int co0 = (blockIdx.x % NCH) * 32;
  const int p = pb * 256 + threadIdx.x;
  float acc[32];
#pragma unroll
  for (int i = 0; i < 32; ++i) acc[i] = 0.f;
  for (int ci = 0; ci < 64; ++ci) {
    float xv = xin[(size_t)ci * N + p];
#pragma unroll
    for (int i = 0; i < 32; ++i) acc[i] = fmaf(xv, W[ci * 128 + co0 + i], acc[i]);
  }
  const int c = p >> 5;
  const bool wlast = (threadIdx.x & 31) == 31;
#pragma unroll
  for (int i = 0; i < 32; ++i) {
    float v = fmaxf(0.f, fmaf(acc[i], sc[co0 + i], sh[co0 + i]));
    DPPMAX(0xB1, 0xf)   // quad_perm xor1
    DPPMAX(0x4E, 0xf)   // quad_perm xor2
    DPPMAX(0x124, 0xf)  // row_ror:4
    DPPMAX(0x128, 0xf)  // row_ror:8
    DPPMAX(0x142, 0xa)  // row_bcast15 -> lanes 31/63 cover their 32-group
    if (wlast) outp[(size_t)c * 128 + co0 + i] = v;
  }
}

extern "C" void kernel_launch(void* const* d_in, const int* in_sizes, int n_in,
                              void* d_out, int out_size, void* d_ws, size_t ws_size,
                              hipStream_t stream) {
  const float* xyz = (const float*)d_in[0];
  const float* pts = (const float*)d_in[1];
  const float* W0 = (const float*)d_in[2];
  const float* b0 = (const float*)d_in[3];
  const float* g0 = (const float*)d_in[4];
  const float* be0 = (const float*)d_in[5];
  const float* W1 = (const float*)d_in[6];
  const float* b1 = (const float*)d_in[7];
  const float* g1 = (const float*)d_in[8];
  const float* be1 = (const float*)d_in[9];
  const float* W2 = (const float*)d_in[10];
  const float* b2 = (const float*)d_in[11];
  const float* g2 = (const float*)d_in[12];
  const float* be2 = (const float*)d_in[13];

  float* out = (float*)d_out;
  float* newxyz = out;                // (B,S,3)
  float* outpts = out + NB * NS * 3;  // (B,S,128)

  float* ws = (float*)d_ws;
  float* x0T = ws;                      // 9N
  float* x1T = ws + (size_t)9 * N;      // 64N
  float* x2T = ws + (size_t)73 * N;     // 64N
  float* scsh = ws + (size_t)137 * N;   // 512 floats
  float* sc1 = scsh, *sh1 = scsh + 64;
  float* sc2 = scsh + 128, *sh2 = scsh + 192;
  float* sc3 = scsh + 256, *sh3 = scsh + 384;
  float* cov0 = x1T;  // 90 floats, consumed by xform1 before mm1 writes x1T
  float* cov1 = x2T;  // 4160 floats, consumed by xform_par before mm2 writes x2T
  float* cov2 = x0T;  // 4160 floats, written after x0T is dead (post-mm1)

  hipMemsetAsync(cov0, 0, 90 * sizeof(float), stream);
  hipMemsetAsync(cov1, 0, 4160 * sizeof(float), stream);

  fps_kernel<<<NB, 256, 0, stream>>>(xyz, newxyz);
  ballq_kernel<<<(NB * NS) / 4, 256, 0, stream>>>(xyz, pts, newxyz, x0T);

  moments9_kernel<<<256, 256, 0, stream>>>(x0T, cov0);
  xform1_kernel<<<1, 64, 0, stream>>>(cov0, W0, b0, g0, be0, sc1, sh1);
  mm_kernel<9, 64><<<(N / 256) * 2, 256, 0, stream>>>(x0T, W0, sc1, sh1, x1T);

  moments64_kernel<<<512, 256, 0, stream>>>(x1T, cov1);
  xform_par_kernel<64><<<64, 256, 0, stream>>>(cov1, W1, b1, g1, be1, sc2, sh2);
  mm_kernel<64, 64><<<(N / 256) * 2, 256, 0, stream>>>(x1T, W1, sc2, sh2, x2T);

  hipMemsetAsync(cov2, 0, 4160 * sizeof(float), stream);
  moments64_kernel<<<512, 256, 0, stream>>>(x2T, cov2);
  xform_par_kernel<128><<<128, 256, 0, stream>>>(cov2, W2, b2, g2, be2, sc3, sh3);
  mm_final_kernel<<<(N / 256) * 4, 256, 0, stream>>>(x2T, W2, sc3, sh3, outpts);
}